// Round 5
// baseline (211.979 us; speedup 1.0000x reference)
//
#include <hip/hip_runtime.h>
#include <hip/hip_bf16.h>
#include <math.h>

// Problem constants (fixed by setup_inputs)
constexpr int B  = 4;
constexpr int Q  = 1024;
constexpr int D  = 256;
constexpr int NH = 8;
constexpr int NP = 4;
constexpr int H  = 128;
constexpr int W  = 128;
constexpr int HW = H * W;
constexpr int KAUG = 2112;          // 8*256 channels + 8 S + 56 zeros (K % 64 == 0)

typedef short   bf16x8  __attribute__((ext_vector_type(8)));
typedef float   f32x4   __attribute__((ext_vector_type(4)));
typedef short   short4v __attribute__((ext_vector_type(4)));
typedef unsigned short ushort4v __attribute__((ext_vector_type(4)));
typedef unsigned short ushort8v __attribute__((ext_vector_type(8)));

__device__ inline unsigned short f2bf(float f) {
    union { float f; unsigned u; } v; v.f = f;
    unsigned r = v.u + 0x7fff + ((v.u >> 16) & 1);   // RNE
    return (unsigned short)(r >> 16);
}
__device__ inline float bf2f(unsigned short s) {
    union { unsigned u; float f; } v; v.u = ((unsigned)s) << 16;
    return v.f;
}

// async global->LDS, 16B per lane. LDS dest = wave-uniform base + lane*16.
__device__ inline void async16(const void* g, void* l) {
    __builtin_amdgcn_global_load_lds(
        (const __attribute__((address_space(1))) unsigned*)g,
        (__attribute__((address_space(3))) unsigned*)l, 16, 0, 0);
}

// ---------------------------------------------------------------------------
// fp32 -> bf16 elementwise convert (vectorized, n % 1024 == 0)
// ---------------------------------------------------------------------------
__global__ __launch_bounds__(256)
void k_conv(const float* __restrict__ src, unsigned short* __restrict__ dst, int n) {
    const int i = (blockIdx.x * 256 + threadIdx.x) * 4;
    if (i >= n) return;
    const float4 v = *(const float4*)&src[i];
    short4v o;
    o.x = (short)f2bf(v.x); o.y = (short)f2bf(v.y);
    o.z = (short)f2bf(v.z); o.w = (short)f2bf(v.w);
    *(short4v*)&dst[i] = o;
}

// ---------------------------------------------------------------------------
// fp32 [K,N] -> bf16 transposed [N,K]
// ---------------------------------------------------------------------------
__global__ __launch_bounds__(256)
void k_convt(const float* __restrict__ src, unsigned short* __restrict__ dst,
             int K, int N) {
    const int i = blockIdx.x * 256 + threadIdx.x;
    if (i >= N * K) return;
    const int n = i / K, k = i % K;
    dst[i] = f2bf(src[(size_t)k * N + n]);
}

// ---------------------------------------------------------------------------
// Border-correction columns of WcT: WcT[n, 2048+h] = sum_j b_v[j]*W_out[h*256+j, n]
// (cols 2056..2111 zeroed). Exact handling of b_v through the commuted pipeline.
// ---------------------------------------------------------------------------
__global__ __launch_bounds__(256)
void k_bvout(const float* __restrict__ b_v, const float* __restrict__ W_out,
             unsigned short* __restrict__ WcT) {
    const int t = blockIdx.x * 256 + threadIdx.x;   // 16384 threads: n = t>>6, c = t&63
    if (t >= 256 * 64) return;
    const int n = t >> 6, c = t & 63;
    float v = 0.0f;
    if (c < 8) {
        #pragma unroll 8
        for (int j = 0; j < D; ++j)
            v += b_v[j] * W_out[((size_t)c * D + j) * D + n];
    }
    WcT[(size_t)n * KAUG + 2048 + c] = f2bf(v);
}

// ---------------------------------------------------------------------------
// bf16 MFMA GEMM, 64x64 tile, BK=64, double-buffered async16 staging,
// XOR-swizzled LDS (chunk c stored at c^(row&7); staging stays lane-contiguous).
// 256 thr = 4 waves in 2x2, each wave 32x32 (2x2 of 16x16x32 frags).
// C[M,N] = A[M,K](lda) @ Bt[N,K](ldb)^T
// OUTMODE 0: fp32 C row-major (ldc) + bias[N]
// OUTMODE 1: bf16 transposed store Wt[col*ldc + z*256 + row]; Bt += z*256 (batched)
// ---------------------------------------------------------------------------
template <int OUTMODE>
__global__ __launch_bounds__(256)
void k_gemm64(const unsigned short* __restrict__ A, int lda,
              const unsigned short* __restrict__ Bt, int ldb,
              const float* __restrict__ bias,
              void* __restrict__ Cout, int ldc, int K) {
    __shared__ __align__(16) unsigned short lds[4][4096];  // As0,Bs0,As1,Bs1

    const int tid  = threadIdx.x;
    const int lane = tid & 63;
    const int w    = tid >> 6;
    const int wm   = w >> 1, wn = w & 1;
    const int m0 = blockIdx.x * 64, n0 = blockIdx.y * 64;
    if (OUTMODE == 1) Bt += (size_t)blockIdx.z * 256;

    // staging: lane l of wave w covers rows w*8+(l>>3) and +32; logical chunk (l&7)^(l>>3)
    const int srow = w * 8 + (lane >> 3);
    const int schk = (lane & 7) ^ (lane >> 3);
    const unsigned short* ag0 = A  + (size_t)(m0 + srow)      * lda + schk * 8;
    const unsigned short* ag1 = A  + (size_t)(m0 + srow + 32) * lda + schk * 8;
    const unsigned short* bg0 = Bt + (size_t)(n0 + srow)      * ldb + schk * 8;
    const unsigned short* bg1 = Bt + (size_t)(n0 + srow + 32) * ldb + schk * 8;
    const int l0 = w * 512 + lane * 8;
    const int l1 = l0 + 2048;

    // fragment offsets (shorts) in [64][64] swizzled buffer
    int aoff[2][2], boff[2][2];
    #pragma unroll
    for (int i = 0; i < 2; ++i)
        #pragma unroll
        for (int kk = 0; kk < 2; ++kk) {
            const int ar = wm * 32 + i * 16 + (lane & 15);
            aoff[i][kk] = ar * 64 + ((((lane >> 4) + kk * 4) ^ (ar & 7)) * 8);
            const int br = wn * 32 + i * 16 + (lane & 15);
            boff[i][kk] = br * 64 + ((((lane >> 4) + kk * 4) ^ (br & 7)) * 8);
        }

    f32x4 acc[2][2];
    #pragma unroll
    for (int i = 0; i < 2; ++i)
        #pragma unroll
        for (int j = 0; j < 2; ++j) acc[i][j] = (f32x4){0.f, 0.f, 0.f, 0.f};

    // preload stage 0
    async16(ag0, &lds[0][l0]); async16(ag1, &lds[0][l1]);
    async16(bg0, &lds[1][l0]); async16(bg1, &lds[1][l1]);

    const int niter = K >> 6;
    for (int it = 0; it < niter; ++it) {
        __syncthreads();                       // drains vmcnt -> stage `it` ready
        const int cur = (it & 1) * 2;
        if (it + 1 < niter) {                  // prefetch next stage during compute
            const int nxt = 2 - cur;
            const int ko  = (it + 1) * 64;
            async16(ag0 + ko, &lds[nxt][l0]);
            async16(ag1 + ko, &lds[nxt][l1]);
            async16(bg0 + ko, &lds[nxt + 1][l0]);
            async16(bg1 + ko, &lds[nxt + 1][l1]);
        }
        bf16x8 af[2][2], bfv[2][2];
        #pragma unroll
        for (int i = 0; i < 2; ++i)
            #pragma unroll
            for (int kk = 0; kk < 2; ++kk) {
                af[i][kk]  = *(const bf16x8*)&lds[cur][aoff[i][kk]];
                bfv[i][kk] = *(const bf16x8*)&lds[cur + 1][boff[i][kk]];
            }
        #pragma unroll
        for (int i = 0; i < 2; ++i)
            #pragma unroll
            for (int j = 0; j < 2; ++j)
                #pragma unroll
                for (int kk = 0; kk < 2; ++kk)
                    acc[i][j] = __builtin_amdgcn_mfma_f32_16x16x32_bf16(
                        af[i][kk], bfv[j][kk], acc[i][j], 0, 0, 0);
    }

    // epilogue: C/D layout col=lane&15, row=(lane>>4)*4+reg
    const int colb = n0 + wn * 32 + (lane & 15);
    const int rowb = m0 + wm * 32 + (lane >> 4) * 4;
    if (OUTMODE == 0) {
        float* C = (float*)Cout;
        #pragma unroll
        for (int j = 0; j < 2; ++j) {
            const int col = colb + j * 16;
            const float bb = bias[col];
            #pragma unroll
            for (int i = 0; i < 2; ++i)
                #pragma unroll
                for (int r = 0; r < 4; ++r)
                    C[(size_t)(rowb + i * 16 + r) * ldc + col] = acc[i][j][r] + bb;
        }
    } else {
        unsigned short* Wt = (unsigned short*)Cout;
        const int ocol = blockIdx.z * 256;
        #pragma unroll
        for (int j = 0; j < 2; ++j) {
            const int col = colb + j * 16;
            #pragma unroll
            for (int i = 0; i < 2; ++i)
                #pragma unroll
                for (int r = 0; r < 4; ++r)
                    Wt[(size_t)col * ldc + ocol + rowb + i * 16 + r] =
                        f2bf(acc[i][j][r]);
        }
    }
}

// ---------------------------------------------------------------------------
// Kernel C (fused): offsets + softmax + bilinear sample + point-reduce -> sv
// One block per (b,q), 256 thr = 4 waves.
// Phase 1a: qrow -> LDS; threads 0..63 compute offset j (dot 256), clip -> s_loc;
//           threads 64..95 compute attn logits -> s_logit.
// Phase 1b: threads 0..31 softmax + corner indices / premultiplied weights -> LDS.
// Phase 2: wave w owns heads {2w,2w+1}. 16B ushort8 loads; half-wave (32 lanes
//          x 8ch) covers one pixel row, so each wave-load fetches TWO corners
//          (c, c+1 of the same (h,p)); halves combined via __shfl_xor(32).
// Also writes S_h (attn-weighted validity sums) to cols 2048+h, zeros to 2111.
// ---------------------------------------------------------------------------
__global__ __launch_bounds__(256)
void k_sample(const unsigned short* __restrict__ val,   // [B,H,W,D] bf16 (raw value)
              const float* __restrict__ query,          // [B,Q,D]
              const float* __restrict__ refpts,         // [B,Q,2]
              const float* __restrict__ W_off,  const float* __restrict__ b_off,
              const float* __restrict__ W_attn, const float* __restrict__ b_attn,
              unsigned short* __restrict__ sv) {        // [B*Q, KAUG] bf16
    const int bq   = blockIdx.x;          // b*Q + q
    const int b    = bq >> 10;            // Q = 1024
    const int tid  = threadIdx.x;
    const int lane = tid & 63;
    const int w    = tid >> 6;

    __shared__ float qrow[D];
    __shared__ float s_loc[64];
    __shared__ float s_logit[NH * NP];
    __shared__ int   s_off[NH * NP][4];   // corner element index (y*W+x), clamped
    __shared__ float s_wgt[NH * NP][4];   // attn * bilinear * valid

    qrow[tid] = query[(size_t)bq * D + tid];
    __syncthreads();

    if (tid < 64) {
        float acc = b_off[tid];
        #pragma unroll 8
        for (int k = 0; k < D; ++k) acc += qrow[k] * W_off[k * 64 + tid];
        const float ref = refpts[(size_t)bq * 2 + (tid & 1)];
        float loc = ref + acc * 0.1f;
        s_loc[tid] = fminf(fmaxf(loc, 0.0f), 1.0f) * 2.0f - 1.0f;
    } else if (tid < 96) {
        const int j = tid - 64;
        float acc = b_attn[j];
        #pragma unroll 8
        for (int k = 0; k < D; ++k) acc += qrow[k] * W_attn[k * 32 + j];
        s_logit[j] = acc;
    }
    __syncthreads();

    if (tid < NH * NP) {
        const int h = tid >> 2;
        float m = -1e30f;
        #pragma unroll
        for (int p = 0; p < NP; ++p) m = fmaxf(m, s_logit[h * NP + p]);
        float s = 0.0f;
        #pragma unroll
        for (int p = 0; p < NP; ++p) s += __expf(s_logit[h * NP + p] - m);
        const float a = __expf(s_logit[tid] - m) / s;

        const float gx = s_loc[tid * 2 + 0];
        const float gy = s_loc[tid * 2 + 1];
        const float x  = ((gx + 1.0f) * (float)W - 1.0f) * 0.5f;
        const float y  = ((gy + 1.0f) * (float)H - 1.0f) * 0.5f;
        const float x0f = floorf(x), y0f = floorf(y);
        const float wx1 = x - x0f,  wy1 = y - y0f;
        const float wx0 = 1.0f - wx1, wy0 = 1.0f - wy1;
        const int x0 = (int)x0f, y0 = (int)y0f;
        const int x1 = x0 + 1,  y1 = y0 + 1;
        const float vx0 = (x0 >= 0 && x0 < W) ? 1.0f : 0.0f;
        const float vx1 = (x1 >= 0 && x1 < W) ? 1.0f : 0.0f;
        const float vy0 = (y0 >= 0 && y0 < H) ? 1.0f : 0.0f;
        const float vy1 = (y1 >= 0 && y1 < H) ? 1.0f : 0.0f;
        const int xc0 = min(max(x0, 0), W - 1);
        const int xc1 = min(max(x1, 0), W - 1);
        const int yc0 = min(max(y0, 0), H - 1);
        const int yc1 = min(max(y1, 0), H - 1);
        s_off[tid][0] = yc0 * W + xc0;
        s_off[tid][1] = yc0 * W + xc1;
        s_off[tid][2] = yc1 * W + xc0;
        s_off[tid][3] = yc1 * W + xc1;
        s_wgt[tid][0] = a * wx0 * wy0 * vx0 * vy0;
        s_wgt[tid][1] = a * wx1 * wy0 * vx1 * vy0;
        s_wgt[tid][2] = a * wx0 * wy1 * vx0 * vy1;
        s_wgt[tid][3] = a * wx1 * wy1 * vx1 * vy1;
    }
    __syncthreads();

    // augmented columns: S_h and zero padding
    if (tid < 8) {
        float S = 0.0f;
        #pragma unroll
        for (int p = 0; p < NP; ++p)
            #pragma unroll
            for (int c = 0; c < 4; ++c) S += s_wgt[tid * 4 + p][c];
        sv[(size_t)bq * KAUG + 2048 + tid] = f2bf(S);
    } else if (tid < 64) {
        sv[(size_t)bq * KAUG + 2048 + tid] = 0;
    }

    // phase 2: gather. half = lane>>5 selects corner parity; l5 = lane&31 owns 8 ch.
    const int half = lane >> 5;
    const int l5   = lane & 31;
    const unsigned short* ib = val + (size_t)b * HW * D + l5 * 8;

    float acc[2][8] = {};
    #pragma unroll
    for (int i = 0; i < 16; ++i) {
        const int cidx = i * 2 + half;         // 0..31 within wave
        const int tl   = cidx >> 2;            // 0..7
        const int c    = cidx & 3;
        const int t    = w * 8 + tl;
        const int hh   = tl >> 2;              // head within wave
        const float wgt = s_wgt[t][c];
        const ushort8v v = *(const ushort8v*)(ib + (size_t)s_off[t][c] * D);
        #pragma unroll
        for (int k = 0; k < 8; ++k) acc[hh][k] += wgt * bf2f(v[k]);
    }

    // combine halves and store (lanes 0..31 write 16B per head)
    #pragma unroll
    for (int hh = 0; hh < 2; ++hh) {
        float comb[8];
        #pragma unroll
        for (int k = 0; k < 8; ++k)
            comb[k] = acc[hh][k] + __shfl_xor(acc[hh][k], 32, 64);
        if (half == 0) {
            const int h = w * 2 + hh;
            ushort8v o;
            #pragma unroll
            for (int k = 0; k < 8; ++k) o[k] = f2bf(comb[k]);
            *(ushort8v*)&sv[(size_t)bq * KAUG + h * D + l5 * 8] = o;
        }
    }
}

// ---------------------------------------------------------------------------
extern "C" void kernel_launch(void* const* d_in, const int* in_sizes, int n_in,
                              void* d_out, int out_size, void* d_ws, size_t ws_size,
                              hipStream_t stream) {
    const float* query  = (const float*)d_in[0];
    const float* refpts = (const float*)d_in[1];
    const float* value  = (const float*)d_in[2];
    const float* W_off  = (const float*)d_in[3];
    const float* b_off  = (const float*)d_in[4];
    const float* W_attn = (const float*)d_in[5];
    const float* b_attn = (const float*)d_in[6];
    const float* W_v    = (const float*)d_in[7];
    const float* b_v    = (const float*)d_in[8];
    const float* W_out  = (const float*)d_in[9];
    const float* b_out  = (const float*)d_in[10];
    float* out = (float*)d_out;

    // workspace layout (byte offsets, all 256B aligned)
    char* wsb = (char*)d_ws;
    unsigned short* val_bf = (unsigned short*)(wsb);             // B*HW*D bf16   = 33,554,432 B
    unsigned short* sv     = (unsigned short*)(wsb + 33554432);  // 4096*2112 bf16= 17,301,504 B
    unsigned short* WcT    = (unsigned short*)(wsb + 50855936);  // 256*2112 bf16 =  1,081,344 B
    unsigned short* Wout_t = (unsigned short*)(wsb + 51937280);  // 256*2048 bf16 =  1,048,576 B
    unsigned short* Wv_bf  = (unsigned short*)(wsb + 52985856);  // 256*256 bf16  =    131,072 B

    // converts
    k_conv<<<(B * HW * D) / 1024, 256, 0, stream>>>(value, val_bf, B * HW * D);
    k_conv<<<(D * D) / 1024, 256, 0, stream>>>(W_v, Wv_bf, D * D);
    k_convt<<<(NH * D * D) / 256, 256, 0, stream>>>(W_out, Wout_t, NH * D, D);

    // Wc_h = W_v @ W_out_h  -> WcT[n, h*256+i] (batched over h = blockIdx.z)
    {
        dim3 grid(D / 64, D / 64, NH);
        k_gemm64<1><<<grid, 256, 0, stream>>>(Wv_bf, D, Wout_t, NH * D,
                                              nullptr, WcT, KAUG, D);
    }
    // WcT border-correction cols (b_v @ W_out_h), cols 2048..2111
    k_bvout<<<64, 256, 0, stream>>>(b_v, W_out, WcT);

    // fused offsets + softmax + sample + point-reduce -> sv [4096, KAUG]
    k_sample<<<B * Q, 256, 0, stream>>>(val_bf, query, refpts, W_off, b_off,
                                        W_attn, b_attn, sv);

    // out = sv @ WcT^T + b_out  (M=4096, N=256, K=2112)
    {
        dim3 grid((B * Q) / 64, D / 64, 1);
        k_gemm64<0><<<grid, 256, 0, stream>>>(sv, KAUG, WcT, KAUG,
                                              b_out, out, D, KAUG);
    }
}

// Round 7
// 203.466 us; speedup vs baseline: 1.0418x; 1.0418x over previous
//
#include <hip/hip_runtime.h>
#include <hip/hip_bf16.h>
#include <math.h>

// Problem constants (fixed by setup_inputs)
constexpr int B  = 4;
constexpr int Q  = 1024;
constexpr int D  = 256;
constexpr int NH = 8;
constexpr int NP = 4;
constexpr int H  = 128;
constexpr int W  = 128;
constexpr int HW = H * W;
constexpr int KAUG = 2112;          // 8*256 channels + 8 S + 56 zeros (K % 64 == 0)

typedef short   bf16x8  __attribute__((ext_vector_type(8)));
typedef float   f32x4   __attribute__((ext_vector_type(4)));
typedef short   short4v __attribute__((ext_vector_type(4)));
typedef unsigned short ushort8v __attribute__((ext_vector_type(8)));

__device__ inline unsigned short f2bf(float f) {
    union { float f; unsigned u; } v; v.f = f;
    unsigned r = v.u + 0x7fff + ((v.u >> 16) & 1);   // RNE
    return (unsigned short)(r >> 16);
}
__device__ inline float bf2f(unsigned short s) {
    union { unsigned u; float f; } v; v.u = ((unsigned)s) << 16;
    return v.f;
}

// async global->LDS, 16B per lane. LDS dest = wave-uniform base + lane*16.
__device__ inline void async16(const void* g, void* l) {
    __builtin_amdgcn_global_load_lds(
        (const __attribute__((address_space(1))) unsigned*)g,
        (__attribute__((address_space(3))) unsigned*)l, 16, 0, 0);
}

// ---------------------------------------------------------------------------
// Mega-prep kernel: block role by blockIdx.x range.
//   [0, 16384)         : value fp32->bf16 (1024 elems/block; 16,777,216 total)
//   [16384, 20480)     : offsets+softmax+corner tables (one block/query, 4096)
//   [20480, 22528)     : W_out [2048,256] -> bf16 transposed Wout_t [256,2048]
//   [22528, 22592)     : W_v fp32->bf16 (1024 elems/block, 65,536 total)
//   [22592, 22656)     : WcT border-correction cols 2048..2111 (b_v @ W_out_h)
// NOTE (R6 bug): value needs B*HW*D/1024 = 16384 blocks, not 4096 — 3/4 of
// val_bf stayed poisoned. Role boundaries below are derived, not hand-typed.
// ---------------------------------------------------------------------------
constexpr int RB_CONV  = 0;
constexpr int RB_OFF   = RB_CONV  + (B * HW * D) / 1024;   // 16384
constexpr int RB_CONVT = RB_OFF   + B * Q;                 // 20480
constexpr int RB_WV    = RB_CONVT + (NH * D * D) / 256;    // 22528
constexpr int RB_BV    = RB_WV    + (D * D) / 1024;        // 22592
constexpr int RB_END   = RB_BV    + (D * 64) / 256;        // 22656

__global__ __launch_bounds__(256)
void k_prep(const float* __restrict__ value,
            const float* __restrict__ query,
            const float* __restrict__ refpts,
            const float* __restrict__ W_off,  const float* __restrict__ b_off,
            const float* __restrict__ W_attn, const float* __restrict__ b_attn,
            const float* __restrict__ b_v,    const float* __restrict__ W_out,
            const float* __restrict__ W_v,
            unsigned short* __restrict__ val_bf,
            int* __restrict__ ctab,           // [B*Q, 32*4] corner indices
            float* __restrict__ wtab,         // [B*Q, 32*4] premultiplied weights
            unsigned short* __restrict__ sv,  // writes augmented cols 2048..2111
            unsigned short* __restrict__ Wout_t,
            unsigned short* __restrict__ Wv_bf,
            unsigned short* __restrict__ WcT) {
    const int blk = blockIdx.x;
    const int tid = threadIdx.x;

    if (blk < RB_OFF) {
        // --- value convert: 1024 elems per block ---
        const int i = (blk * 1024) + tid * 4;
        const float4 v = *(const float4*)&value[i];
        short4v o;
        o.x = (short)f2bf(v.x); o.y = (short)f2bf(v.y);
        o.z = (short)f2bf(v.z); o.w = (short)f2bf(v.w);
        *(short4v*)&val_bf[i] = o;
    } else if (blk < RB_CONVT) {
        // --- offsets / attn / corner tables for one query ---
        const int bq = blk - RB_OFF;
        __shared__ float qrow[D];
        __shared__ float s_loc[64];
        __shared__ float s_logit[NH * NP];
        __shared__ float s_wgt[NH * NP][4];

        qrow[tid] = query[(size_t)bq * D + tid];
        __syncthreads();

        if (tid < 64) {
            float acc = b_off[tid];
            #pragma unroll 8
            for (int k = 0; k < D; ++k) acc += qrow[k] * W_off[k * 64 + tid];
            const float ref = refpts[(size_t)bq * 2 + (tid & 1)];
            float loc = ref + acc * 0.1f;
            s_loc[tid] = fminf(fmaxf(loc, 0.0f), 1.0f) * 2.0f - 1.0f;
        } else if (tid < 96) {
            const int j = tid - 64;
            float acc = b_attn[j];
            #pragma unroll 8
            for (int k = 0; k < D; ++k) acc += qrow[k] * W_attn[k * 32 + j];
            s_logit[j] = acc;
        }
        __syncthreads();

        if (tid < NH * NP) {
            const int h = tid >> 2;
            float m = -1e30f;
            #pragma unroll
            for (int p = 0; p < NP; ++p) m = fmaxf(m, s_logit[h * NP + p]);
            float s = 0.0f;
            #pragma unroll
            for (int p = 0; p < NP; ++p) s += __expf(s_logit[h * NP + p] - m);
            const float a = __expf(s_logit[tid] - m) / s;

            const float gx = s_loc[tid * 2 + 0];
            const float gy = s_loc[tid * 2 + 1];
            const float x  = ((gx + 1.0f) * (float)W - 1.0f) * 0.5f;
            const float y  = ((gy + 1.0f) * (float)H - 1.0f) * 0.5f;
            const float x0f = floorf(x), y0f = floorf(y);
            const float wx1 = x - x0f,  wy1 = y - y0f;
            const float wx0 = 1.0f - wx1, wy0 = 1.0f - wy1;
            const int x0 = (int)x0f, y0 = (int)y0f;
            const int x1 = x0 + 1,  y1 = y0 + 1;
            const float vx0 = (x0 >= 0 && x0 < W) ? 1.0f : 0.0f;
            const float vx1 = (x1 >= 0 && x1 < W) ? 1.0f : 0.0f;
            const float vy0 = (y0 >= 0 && y0 < H) ? 1.0f : 0.0f;
            const float vy1 = (y1 >= 0 && y1 < H) ? 1.0f : 0.0f;
            const int xc0 = min(max(x0, 0), W - 1);
            const int xc1 = min(max(x1, 0), W - 1);
            const int yc0 = min(max(y0, 0), H - 1);
            const int yc1 = min(max(y1, 0), H - 1);
            int   offs[4];
            float wgts[4];
            offs[0] = yc0 * W + xc0;  wgts[0] = a * wx0 * wy0 * vx0 * vy0;
            offs[1] = yc0 * W + xc1;  wgts[1] = a * wx1 * wy0 * vx1 * vy0;
            offs[2] = yc1 * W + xc0;  wgts[2] = a * wx0 * wy1 * vx0 * vy1;
            offs[3] = yc1 * W + xc1;  wgts[3] = a * wx1 * wy1 * vx1 * vy1;
            #pragma unroll
            for (int c = 0; c < 4; ++c) {
                ctab[(size_t)bq * 128 + tid * 4 + c] = offs[c];
                wtab[(size_t)bq * 128 + tid * 4 + c] = wgts[c];
                s_wgt[tid][c] = wgts[c];
            }
        }
        __syncthreads();

        // augmented columns of sv: S_h + zero pad
        if (tid < 8) {
            float S = 0.0f;
            #pragma unroll
            for (int p = 0; p < NP; ++p)
                #pragma unroll
                for (int c = 0; c < 4; ++c) S += s_wgt[tid * 4 + p][c];
            sv[(size_t)bq * KAUG + 2048 + tid] = f2bf(S);
        } else if (tid < 64) {
            sv[(size_t)bq * KAUG + 2048 + tid] = 0;
        }
    } else if (blk < RB_WV) {
        // --- W_out [2048,256] -> Wout_t [256,2048] bf16 ---
        const int i = (blk - RB_CONVT) * 256 + tid;   // i = n*2048 + k
        const int n = i >> 11, k = i & 2047;
        Wout_t[i] = f2bf(W_out[(size_t)k * D + n]);
    } else if (blk < RB_BV) {
        // --- W_v fp32->bf16, 1024 elems/block ---
        const int i = (blk - RB_WV) * 1024 + tid * 4;
        const float4 v = *(const float4*)&W_v[i];
        short4v o;
        o.x = (short)f2bf(v.x); o.y = (short)f2bf(v.y);
        o.z = (short)f2bf(v.z); o.w = (short)f2bf(v.w);
        *(short4v*)&Wv_bf[i] = o;
    } else {
        // --- WcT border-correction cols: WcT[n, 2048+c] = b_v . W_out[c*256.., n] ---
        const int t = (blk - RB_BV) * 256 + tid;      // n = t>>6, c = t&63
        const int n = t >> 6, c = t & 63;
        float v = 0.0f;
        if (c < 8) {
            #pragma unroll 8
            for (int j = 0; j < D; ++j)
                v += b_v[j] * W_out[((size_t)c * D + j) * D + n];
        }
        WcT[(size_t)n * KAUG + 2048 + c] = f2bf(v);
    }
}

// ---------------------------------------------------------------------------
// bf16 MFMA GEMM, 64x64 tile, BK=64, double-buffered async16 staging,
// XOR-swizzled LDS (chunk c stored at c^(row&7); staging stays lane-contiguous).
// 256 thr = 4 waves in 2x2, each wave 32x32 (2x2 of 16x16x32 frags).
// C[M,N] = A[M,K](lda) @ Bt[N,K](ldb)^T
// OUTMODE 0: fp32 C row-major (ldc) + bias[N]
// OUTMODE 1: bf16 transposed store Wt[col*ldc + z*256 + row]; Bt += z*256 (batched)
// ---------------------------------------------------------------------------
template <int OUTMODE>
__global__ __launch_bounds__(256)
void k_gemm64(const unsigned short* __restrict__ A, int lda,
              const unsigned short* __restrict__ Bt, int ldb,
              const float* __restrict__ bias,
              void* __restrict__ Cout, int ldc, int K) {
    __shared__ __align__(16) unsigned short lds[4][4096];  // As0,Bs0,As1,Bs1

    const int tid  = threadIdx.x;
    const int lane = tid & 63;
    const int w    = tid >> 6;
    const int wm   = w >> 1, wn = w & 1;
    const int m0 = blockIdx.x * 64, n0 = blockIdx.y * 64;
    if (OUTMODE == 1) Bt += (size_t)blockIdx.z * 256;

    // staging: lane l of wave w covers rows w*8+(l>>3) and +32; logical chunk (l&7)^(l>>3)
    const int srow = w * 8 + (lane >> 3);
    const int schk = (lane & 7) ^ (lane >> 3);
    const unsigned short* ag0 = A  + (size_t)(m0 + srow)      * lda + schk * 8;
    const unsigned short* ag1 = A  + (size_t)(m0 + srow + 32) * lda + schk * 8;
    const unsigned short* bg0 = Bt + (size_t)(n0 + srow)      * ldb + schk * 8;
    const unsigned short* bg1 = Bt + (size_t)(n0 + srow + 32) * ldb + schk * 8;
    const int l0 = w * 512 + lane * 8;
    const int l1 = l0 + 2048;

    // fragment offsets (shorts) in [64][64] swizzled buffer
    int aoff[2][2], boff[2][2];
    #pragma unroll
    for (int i = 0; i < 2; ++i)
        #pragma unroll
        for (int kk = 0; kk < 2; ++kk) {
            const int ar = wm * 32 + i * 16 + (lane & 15);
            aoff[i][kk] = ar * 64 + ((((lane >> 4) + kk * 4) ^ (ar & 7)) * 8);
            const int br = wn * 32 + i * 16 + (lane & 15);
            boff[i][kk] = br * 64 + ((((lane >> 4) + kk * 4) ^ (br & 7)) * 8);
        }

    f32x4 acc[2][2];
    #pragma unroll
    for (int i = 0; i < 2; ++i)
        #pragma unroll
        for (int j = 0; j < 2; ++j) acc[i][j] = (f32x4){0.f, 0.f, 0.f, 0.f};

    // preload stage 0
    async16(ag0, &lds[0][l0]); async16(ag1, &lds[0][l1]);
    async16(bg0, &lds[1][l0]); async16(bg1, &lds[1][l1]);

    const int niter = K >> 6;
    for (int it = 0; it < niter; ++it) {
        __syncthreads();                       // drains vmcnt -> stage `it` ready
        const int cur = (it & 1) * 2;
        if (it + 1 < niter) {                  // prefetch next stage during compute
            const int nxt = 2 - cur;
            const int ko  = (it + 1) * 64;
            async16(ag0 + ko, &lds[nxt][l0]);
            async16(ag1 + ko, &lds[nxt][l1]);
            async16(bg0 + ko, &lds[nxt + 1][l0]);
            async16(bg1 + ko, &lds[nxt + 1][l1]);
        }
        bf16x8 af[2][2], bfv[2][2];
        #pragma unroll
        for (int i = 0; i < 2; ++i)
            #pragma unroll
            for (int kk = 0; kk < 2; ++kk) {
                af[i][kk]  = *(const bf16x8*)&lds[cur][aoff[i][kk]];
                bfv[i][kk] = *(const bf16x8*)&lds[cur + 1][boff[i][kk]];
            }
        #pragma unroll
        for (int i = 0; i < 2; ++i)
            #pragma unroll
            for (int j = 0; j < 2; ++j)
                #pragma unroll
                for (int kk = 0; kk < 2; ++kk)
                    acc[i][j] = __builtin_amdgcn_mfma_f32_16x16x32_bf16(
                        af[i][kk], bfv[j][kk], acc[i][j], 0, 0, 0);
    }

    // epilogue: C/D layout col=lane&15, row=(lane>>4)*4+reg
    const int colb = n0 + wn * 32 + (lane & 15);
    const int rowb = m0 + wm * 32 + (lane >> 4) * 4;
    if (OUTMODE == 0) {
        float* C = (float*)Cout;
        #pragma unroll
        for (int j = 0; j < 2; ++j) {
            const int col = colb + j * 16;
            const float bb = bias[col];
            #pragma unroll
            for (int i = 0; i < 2; ++i)
                #pragma unroll
                for (int r = 0; r < 4; ++r)
                    C[(size_t)(rowb + i * 16 + r) * ldc + col] = acc[i][j][r] + bb;
        }
    } else {
        unsigned short* Wt = (unsigned short*)Cout;
        const int ocol = blockIdx.z * 256;
        #pragma unroll
        for (int j = 0; j < 2; ++j) {
            const int col = colb + j * 16;
            #pragma unroll
            for (int i = 0; i < 2; ++i)
                #pragma unroll
                for (int r = 0; r < 4; ++r)
                    Wt[(size_t)col * ldc + ocol + rowb + i * 16 + r] =
                        f2bf(acc[i][j][r]);
        }
    }
}

// ---------------------------------------------------------------------------
// Kernel C: bilinear gather + point-reduce using precomputed tables -> sv
// One block per (b,q), 256 thr = 4 waves; wave w owns heads {2w, 2w+1}.
// 16B ushort8 loads; half-wave (32 lanes x 8 ch) covers one pixel row, so each
// wave-load fetches TWO corners (c, c+1 of same (h,p)); halves combined via
// __shfl_xor(32). Loads explicitly batched 8-deep for memory-level parallelism.
// ---------------------------------------------------------------------------
__global__ __launch_bounds__(256)
void k_sample(const unsigned short* __restrict__ val,   // [B,H,W,D] bf16
              const int* __restrict__ ctab,             // [B*Q,128]
              const float* __restrict__ wtab,           // [B*Q,128]
              unsigned short* __restrict__ sv) {        // [B*Q, KAUG] bf16
    const int bq   = blockIdx.x;          // b*Q + q
    const int b    = bq >> 10;            // Q = 1024
    const int tid  = threadIdx.x;
    const int lane = tid & 63;
    const int w    = tid >> 6;

    __shared__ int   s_off[128];
    __shared__ float s_wgt[128];
    if (tid < 128) {
        s_off[tid] = ctab[(size_t)bq * 128 + tid];
        s_wgt[tid] = wtab[(size_t)bq * 128 + tid];
    }
    __syncthreads();

    const int half = lane >> 5;           // corner parity
    const int l5   = lane & 31;           // owns 8 channels
    const unsigned short* ib = val + (size_t)b * HW * D + l5 * 8;

    float acc[2][8] = {};
    #pragma unroll
    for (int g = 0; g < 2; ++g) {         // g == head-within-wave
        ushort8v vb[8];
        float    wg[8];
        #pragma unroll
        for (int j = 0; j < 8; ++j) {     // 8 loads in flight
            const int flat = w * 32 + (g * 8 + j) * 2 + half;  // (h,p,c) flat
            wg[j] = s_wgt[flat];
            vb[j] = *(const ushort8v*)(ib + (size_t)s_off[flat] * D);
        }
        #pragma unroll
        for (int j = 0; j < 8; ++j)
            #pragma unroll
            for (int k = 0; k < 8; ++k)
                acc[g][k] += wg[j] * bf2f(vb[j][k]);
    }

    // combine halves and store (lanes 0..31 write 16B per head)
    #pragma unroll
    for (int hh = 0; hh < 2; ++hh) {
        float comb[8];
        #pragma unroll
        for (int k = 0; k < 8; ++k)
            comb[k] = acc[hh][k] + __shfl_xor(acc[hh][k], 32, 64);
        if (half == 0) {
            const int h = w * 2 + hh;
            ushort8v o;
            #pragma unroll
            for (int k = 0; k < 8; ++k) o[k] = f2bf(comb[k]);
            *(ushort8v*)&sv[(size_t)bq * KAUG + h * D + l5 * 8] = o;
        }
    }
}

// ---------------------------------------------------------------------------
extern "C" void kernel_launch(void* const* d_in, const int* in_sizes, int n_in,
                              void* d_out, int out_size, void* d_ws, size_t ws_size,
                              hipStream_t stream) {
    const float* query  = (const float*)d_in[0];
    const float* refpts = (const float*)d_in[1];
    const float* value  = (const float*)d_in[2];
    const float* W_off  = (const float*)d_in[3];
    const float* b_off  = (const float*)d_in[4];
    const float* W_attn = (const float*)d_in[5];
    const float* b_attn = (const float*)d_in[6];
    const float* W_v    = (const float*)d_in[7];
    const float* b_v    = (const float*)d_in[8];
    const float* W_out  = (const float*)d_in[9];
    const float* b_out  = (const float*)d_in[10];
    float* out = (float*)d_out;

    // workspace layout (byte offsets, all 256B aligned)
    char* wsb = (char*)d_ws;
    unsigned short* val_bf = (unsigned short*)(wsb);             // 33,554,432 B
    unsigned short* sv     = (unsigned short*)(wsb + 33554432);  // 17,301,504 B
    unsigned short* WcT    = (unsigned short*)(wsb + 50855936);  //  1,081,344 B
    unsigned short* Wout_t = (unsigned short*)(wsb + 51937280);  //  1,048,576 B
    unsigned short* Wv_bf  = (unsigned short*)(wsb + 52985856);  //    131,072 B
    int*            ctab   = (int*)(wsb + 53116928);             //  2,097,152 B
    float*          wtab   = (float*)(wsb + 55214080);           //  2,097,152 B

    // 1: mega-prep (value conv | offsets/corner tables | W_out^T | W_v conv | b_v cols)
    k_prep<<<RB_END, 256, 0, stream>>>(value, query, refpts, W_off, b_off,
                                       W_attn, b_attn, b_v, W_out, W_v,
                                       val_bf, ctab, wtab, sv, Wout_t, Wv_bf, WcT);

    // 2: Wc_h = W_v @ W_out_h  -> WcT[n, h*256+i] (batched over h = blockIdx.z)
    {
        dim3 grid(D / 64, D / 64, NH);
        k_gemm64<1><<<grid, 256, 0, stream>>>(Wv_bf, D, Wout_t, NH * D,
                                              nullptr, WcT, KAUG, D);
    }

    // 3: gather + point-reduce -> sv [4096, KAUG]
    k_sample<<<B * Q, 256, 0, stream>>>(val_bf, ctab, wtab, sv);

    // 4: out = sv @ WcT^T + b_out  (M=4096, N=256, K=2112)
    {
        dim3 grid((B * Q) / 64, D / 64, 1);
        k_gemm64<0><<<grid, 256, 0, stream>>>(sv, KAUG, WcT, KAUG,
                                              b_out, out, D, KAUG);
    }
}

// Round 8
// 197.162 us; speedup vs baseline: 1.0752x; 1.0320x over previous
//
#include <hip/hip_runtime.h>
#include <hip/hip_bf16.h>
#include <math.h>

// Problem constants (fixed by setup_inputs)
constexpr int B  = 4;
constexpr int Q  = 1024;
constexpr int D  = 256;
constexpr int NH = 8;
constexpr int NP = 4;
constexpr int H  = 128;
constexpr int W  = 128;
constexpr int HW = H * W;
constexpr int KAUG = 2112;          // 8*256 channels + 8 S + 56 zeros (K % 64 == 0)

typedef short   bf16x8  __attribute__((ext_vector_type(8)));
typedef float   f32x4   __attribute__((ext_vector_type(4)));
typedef short   short4v __attribute__((ext_vector_type(4)));
typedef unsigned short ushort8v __attribute__((ext_vector_type(8)));

__device__ inline unsigned short f2bf(float f) {
    union { float f; unsigned u; } v; v.f = f;
    unsigned r = v.u + 0x7fff + ((v.u >> 16) & 1);   // RNE
    return (unsigned short)(r >> 16);
}
__device__ inline float bf2f(unsigned short s) {
    union { unsigned u; float f; } v; v.u = ((unsigned)s) << 16;
    return v.f;
}

// async global->LDS, 16B per lane. LDS dest = wave-uniform base + lane*16.
__device__ inline void async16(const void* g, void* l) {
    __builtin_amdgcn_global_load_lds(
        (const __attribute__((address_space(1))) unsigned*)g,
        (__attribute__((address_space(3))) unsigned*)l, 16, 0, 0);
}

// ---------------------------------------------------------------------------
// Mega-prep kernel (streaming roles ONLY — no serial dot products; R7's
// offsets-dot role was latency-bound and gated the dispatch at 60us).
//   [0, 16384)      : value fp32->bf16 (1024 elems/block)
//   [16384, 16512)  : Woa [256,128] fp32 = [W_off | W_attn | 0] assembly
//   [16512, 16513)  : bias_oa [128] = [b_off | b_attn | 0]
//   [16513, 18561)  : W_out [2048,256] -> bf16 transposed Wout_t [256,2048]
//   [18561, 18625)  : W_v fp32->bf16
//   [18625, 18689)  : WcT border-correction cols 2048..2111 (b_v @ W_out_h)
// ---------------------------------------------------------------------------
constexpr int RB_CONV  = 0;
constexpr int RB_WOA   = RB_CONV  + (B * HW * D) / 1024;   // 16384
constexpr int RB_BIAS  = RB_WOA   + (D * 128) / 256;       // 16512
constexpr int RB_CONVT = RB_BIAS  + 1;                     // 16513
constexpr int RB_WV    = RB_CONVT + (NH * D * D) / 256;    // 18561
constexpr int RB_BV    = RB_WV    + (D * D) / 1024;        // 18625
constexpr int RB_END   = RB_BV    + (D * 64) / 256;        // 18689

__global__ __launch_bounds__(256)
void k_prep(const float* __restrict__ value,
            const float* __restrict__ W_off,  const float* __restrict__ b_off,
            const float* __restrict__ W_attn, const float* __restrict__ b_attn,
            const float* __restrict__ b_v,    const float* __restrict__ W_out,
            const float* __restrict__ W_v,
            unsigned short* __restrict__ val_bf,
            float* __restrict__ Woa,          // [256,128] fp32
            float* __restrict__ bias_oa,      // [128] fp32
            unsigned short* __restrict__ Wout_t,
            unsigned short* __restrict__ Wv_bf,
            unsigned short* __restrict__ WcT) {
    const int blk = blockIdx.x;
    const int tid = threadIdx.x;

    if (blk < RB_WOA) {
        // --- value convert: 1024 elems per block ---
        const int i = (blk * 1024) + tid * 4;
        const float4 v = *(const float4*)&value[i];
        short4v o;
        o.x = (short)f2bf(v.x); o.y = (short)f2bf(v.y);
        o.z = (short)f2bf(v.z); o.w = (short)f2bf(v.w);
        *(short4v*)&val_bf[i] = o;
    } else if (blk < RB_BIAS) {
        // --- Woa[k][j]: j<64 -> W_off[k*64+j]; j<96 -> W_attn[k*32+j-64]; else 0
        const int i = (blk - RB_WOA) * 256 + tid;     // i = k*128 + j
        const int k = i >> 7, j = i & 127;
        float v = 0.0f;
        if (j < 64)      v = W_off[k * 64 + j];
        else if (j < 96) v = W_attn[k * 32 + (j - 64)];
        Woa[i] = v;
    } else if (blk < RB_CONVT) {
        // --- bias_oa ---
        if (tid < 128) {
            float v = 0.0f;
            if (tid < 64)      v = b_off[tid];
            else if (tid < 96) v = b_attn[tid - 64];
            bias_oa[tid] = v;
        }
    } else if (blk < RB_WV) {
        // --- W_out [2048,256] -> Wout_t [256,2048] bf16 ---
        const int i = (blk - RB_CONVT) * 256 + tid;   // i = n*2048 + k
        const int n = i >> 11, k = i & 2047;
        Wout_t[i] = f2bf(W_out[(size_t)k * D + n]);
    } else if (blk < RB_BV) {
        // --- W_v fp32->bf16, 1024 elems/block ---
        const int i = (blk - RB_WV) * 1024 + tid * 4;
        const float4 v = *(const float4*)&W_v[i];
        short4v o;
        o.x = (short)f2bf(v.x); o.y = (short)f2bf(v.y);
        o.z = (short)f2bf(v.z); o.w = (short)f2bf(v.w);
        *(short4v*)&Wv_bf[i] = o;
    } else {
        // --- WcT border-correction cols: WcT[n, 2048+c] = b_v . W_out[c*256.., n] ---
        const int t = (blk - RB_BV) * 256 + tid;      // n = t>>6, c = t&63
        const int n = t >> 6, c = t & 63;
        float v = 0.0f;
        if (c < 8) {
            #pragma unroll 8
            for (int j = 0; j < D; ++j)
                v += b_v[j] * W_out[((size_t)c * D + j) * D + n];
        }
        WcT[(size_t)n * KAUG + 2048 + c] = f2bf(v);
    }
}

// ---------------------------------------------------------------------------
// fp32 SGEMM (vector ALU — exact fp32 numerics for offsets/logits).
// C[M,N] = A[M,K] @ Bm[K,N] + bias[N]. 64x64 tile, 256 thr, 4x4 micro, BK=16.
// ---------------------------------------------------------------------------
#define BM 64
#define BN 64
#define BK 16

__global__ __launch_bounds__(256)
void k_sgemm(const float* __restrict__ A, const float* __restrict__ Bm,
             const float* __restrict__ bias, float* __restrict__ C,
             int M, int N, int K) {
    __shared__ __align__(16) float As[BK][BM + 4];
    __shared__ __align__(16) float Bs[BK][BN + 4];

    const int t  = threadIdx.x;
    const int tx = t & 15;
    const int ty = t >> 4;
    const int m0 = blockIdx.x * BM;
    const int n0 = blockIdx.y * BN;

    const int arow = t >> 2;
    const int akg  = (t & 3) * 4;
    const int brow = t >> 4;
    const int bcol = (t & 15) * 4;

    float acc[4][4] = {};

    for (int k0 = 0; k0 < K; k0 += BK) {
        const float4 av = *(const float4*)&A[(size_t)(m0 + arow) * K + k0 + akg];
        const float4 bv = *(const float4*)&Bm[(size_t)(k0 + brow) * N + n0 + bcol];
        __syncthreads();
        As[akg + 0][arow] = av.x;
        As[akg + 1][arow] = av.y;
        As[akg + 2][arow] = av.z;
        As[akg + 3][arow] = av.w;
        *(float4*)&Bs[brow][bcol] = bv;
        __syncthreads();

        #pragma unroll
        for (int kk = 0; kk < BK; ++kk) {
            const float4 a = *(const float4*)&As[kk][ty * 4];
            const float4 b = *(const float4*)&Bs[kk][tx * 4];
            acc[0][0] += a.x * b.x; acc[0][1] += a.x * b.y; acc[0][2] += a.x * b.z; acc[0][3] += a.x * b.w;
            acc[1][0] += a.y * b.x; acc[1][1] += a.y * b.y; acc[1][2] += a.y * b.z; acc[1][3] += a.y * b.w;
            acc[2][0] += a.z * b.x; acc[2][1] += a.z * b.y; acc[2][2] += a.z * b.z; acc[2][3] += a.z * b.w;
            acc[3][0] += a.w * b.x; acc[3][1] += a.w * b.y; acc[3][2] += a.w * b.z; acc[3][3] += a.w * b.w;
        }
    }

    const float4 bb = *(const float4*)&bias[n0 + tx * 4];
    #pragma unroll
    for (int i = 0; i < 4; ++i) {
        const int m = m0 + ty * 4 + i;
        float4 r;
        r.x = acc[i][0] + bb.x;
        r.y = acc[i][1] + bb.y;
        r.z = acc[i][2] + bb.z;
        r.w = acc[i][3] + bb.w;
        *(float4*)&C[(size_t)m * N + n0 + tx * 4] = r;
    }
}

// ---------------------------------------------------------------------------
// bf16 MFMA GEMM, 64x64 tile, BK=64, double-buffered async16 staging,
// XOR-swizzled LDS. C[M,N] = A[M,K](lda) @ Bt[N,K](ldb)^T
// OUTMODE 0: fp32 C row-major (ldc) + bias[N]
// OUTMODE 1: bf16 transposed store Wt[col*ldc + z*256 + row]; Bt += z*256
// ---------------------------------------------------------------------------
template <int OUTMODE>
__global__ __launch_bounds__(256)
void k_gemm64(const unsigned short* __restrict__ A, int lda,
              const unsigned short* __restrict__ Bt, int ldb,
              const float* __restrict__ bias,
              void* __restrict__ Cout, int ldc, int K) {
    __shared__ __align__(16) unsigned short lds[4][4096];  // As0,Bs0,As1,Bs1

    const int tid  = threadIdx.x;
    const int lane = tid & 63;
    const int w    = tid >> 6;
    const int wm   = w >> 1, wn = w & 1;
    const int m0 = blockIdx.x * 64, n0 = blockIdx.y * 64;
    if (OUTMODE == 1) Bt += (size_t)blockIdx.z * 256;

    const int srow = w * 8 + (lane >> 3);
    const int schk = (lane & 7) ^ (lane >> 3);
    const unsigned short* ag0 = A  + (size_t)(m0 + srow)      * lda + schk * 8;
    const unsigned short* ag1 = A  + (size_t)(m0 + srow + 32) * lda + schk * 8;
    const unsigned short* bg0 = Bt + (size_t)(n0 + srow)      * ldb + schk * 8;
    const unsigned short* bg1 = Bt + (size_t)(n0 + srow + 32) * ldb + schk * 8;
    const int l0 = w * 512 + lane * 8;
    const int l1 = l0 + 2048;

    int aoff[2][2], boff[2][2];
    #pragma unroll
    for (int i = 0; i < 2; ++i)
        #pragma unroll
        for (int kk = 0; kk < 2; ++kk) {
            const int ar = wm * 32 + i * 16 + (lane & 15);
            aoff[i][kk] = ar * 64 + ((((lane >> 4) + kk * 4) ^ (ar & 7)) * 8);
            const int br = wn * 32 + i * 16 + (lane & 15);
            boff[i][kk] = br * 64 + ((((lane >> 4) + kk * 4) ^ (br & 7)) * 8);
        }

    f32x4 acc[2][2];
    #pragma unroll
    for (int i = 0; i < 2; ++i)
        #pragma unroll
        for (int j = 0; j < 2; ++j) acc[i][j] = (f32x4){0.f, 0.f, 0.f, 0.f};

    async16(ag0, &lds[0][l0]); async16(ag1, &lds[0][l1]);
    async16(bg0, &lds[1][l0]); async16(bg1, &lds[1][l1]);

    const int niter = K >> 6;
    for (int it = 0; it < niter; ++it) {
        __syncthreads();
        const int cur = (it & 1) * 2;
        if (it + 1 < niter) {
            const int nxt = 2 - cur;
            const int ko  = (it + 1) * 64;
            async16(ag0 + ko, &lds[nxt][l0]);
            async16(ag1 + ko, &lds[nxt][l1]);
            async16(bg0 + ko, &lds[nxt + 1][l0]);
            async16(bg1 + ko, &lds[nxt + 1][l1]);
        }
        bf16x8 af[2][2], bfv[2][2];
        #pragma unroll
        for (int i = 0; i < 2; ++i)
            #pragma unroll
            for (int kk = 0; kk < 2; ++kk) {
                af[i][kk]  = *(const bf16x8*)&lds[cur][aoff[i][kk]];
                bfv[i][kk] = *(const bf16x8*)&lds[cur + 1][boff[i][kk]];
            }
        #pragma unroll
        for (int i = 0; i < 2; ++i)
            #pragma unroll
            for (int j = 0; j < 2; ++j)
                #pragma unroll
                for (int kk = 0; kk < 2; ++kk)
                    acc[i][j] = __builtin_amdgcn_mfma_f32_16x16x32_bf16(
                        af[i][kk], bfv[j][kk], acc[i][j], 0, 0, 0);
    }

    const int colb = n0 + wn * 32 + (lane & 15);
    const int rowb = m0 + wm * 32 + (lane >> 4) * 4;
    if (OUTMODE == 0) {
        float* C = (float*)Cout;
        #pragma unroll
        for (int j = 0; j < 2; ++j) {
            const int col = colb + j * 16;
            const float bb = bias[col];
            #pragma unroll
            for (int i = 0; i < 2; ++i)
                #pragma unroll
                for (int r = 0; r < 4; ++r)
                    C[(size_t)(rowb + i * 16 + r) * ldc + col] = acc[i][j][r] + bb;
        }
    } else {
        unsigned short* Wt = (unsigned short*)Cout;
        const int ocol = blockIdx.z * 256;
        #pragma unroll
        for (int j = 0; j < 2; ++j) {
            const int col = colb + j * 16;
            #pragma unroll
            for (int i = 0; i < 2; ++i)
                #pragma unroll
                for (int r = 0; r < 4; ++r)
                    Wt[(size_t)col * ldc + ocol + rowb + i * 16 + r] =
                        f2bf(acc[i][j][r]);
        }
    }
}

// ---------------------------------------------------------------------------
// Kernel C: phase 1 (cheap): softmax + corner tables from raw GEMM output;
// phase 2: bilinear gather + point-reduce -> sv.
// One block per (b,q), 256 thr = 4 waves; wave w owns heads {2w, 2w+1}.
// 16B ushort8 loads; half-wave covers one pixel row -> each wave-load fetches
// TWO corners; halves combined via __shfl_xor(32). Loads batched 8-deep.
// ---------------------------------------------------------------------------
__global__ __launch_bounds__(256)
void k_sample(const unsigned short* __restrict__ val,   // [B,H,W,D] bf16
              const float* __restrict__ raw,            // [B*Q,128] offsets|logits
              const float* __restrict__ refpts,         // [B,Q,2]
              unsigned short* __restrict__ sv) {        // [B*Q, KAUG] bf16
    const int bq   = blockIdx.x;          // b*Q + q
    const int b    = bq >> 10;            // Q = 1024
    const int tid  = threadIdx.x;
    const int lane = tid & 63;
    const int w    = tid >> 6;

    __shared__ float s_raw[128];
    __shared__ int   s_off[128];          // [hp*4+c] corner indices
    __shared__ float s_wgt[128];          // [hp*4+c] premultiplied weights

    if (tid < 128) s_raw[tid] = raw[(size_t)bq * 128 + tid];
    __syncthreads();

    if (tid < NH * NP) {                  // tid == hp
        const int h = tid >> 2;
        float m = -1e30f;
        #pragma unroll
        for (int p = 0; p < NP; ++p) m = fmaxf(m, s_raw[64 + h * 4 + p]);
        float s = 0.0f;
        #pragma unroll
        for (int p = 0; p < NP; ++p) s += __expf(s_raw[64 + h * 4 + p] - m);
        const float a = __expf(s_raw[64 + tid] - m) / s;

        const float refx = refpts[(size_t)bq * 2 + 0];
        const float refy = refpts[(size_t)bq * 2 + 1];
        const float gx = fminf(fmaxf(refx + s_raw[tid * 2 + 0] * 0.1f, 0.0f), 1.0f) * 2.0f - 1.0f;
        const float gy = fminf(fmaxf(refy + s_raw[tid * 2 + 1] * 0.1f, 0.0f), 1.0f) * 2.0f - 1.0f;
        const float x  = ((gx + 1.0f) * (float)W - 1.0f) * 0.5f;
        const float y  = ((gy + 1.0f) * (float)H - 1.0f) * 0.5f;
        const float x0f = floorf(x), y0f = floorf(y);
        const float wx1 = x - x0f,  wy1 = y - y0f;
        const float wx0 = 1.0f - wx1, wy0 = 1.0f - wy1;
        const int x0 = (int)x0f, y0 = (int)y0f;
        const int x1 = x0 + 1,  y1 = y0 + 1;
        const float vx0 = (x0 >= 0 && x0 < W) ? 1.0f : 0.0f;
        const float vx1 = (x1 >= 0 && x1 < W) ? 1.0f : 0.0f;
        const float vy0 = (y0 >= 0 && y0 < H) ? 1.0f : 0.0f;
        const float vy1 = (y1 >= 0 && y1 < H) ? 1.0f : 0.0f;
        const int xc0 = min(max(x0, 0), W - 1);
        const int xc1 = min(max(x1, 0), W - 1);
        const int yc0 = min(max(y0, 0), H - 1);
        const int yc1 = min(max(y1, 0), H - 1);
        s_off[tid * 4 + 0] = yc0 * W + xc0;
        s_off[tid * 4 + 1] = yc0 * W + xc1;
        s_off[tid * 4 + 2] = yc1 * W + xc0;
        s_off[tid * 4 + 3] = yc1 * W + xc1;
        s_wgt[tid * 4 + 0] = a * wx0 * wy0 * vx0 * vy0;
        s_wgt[tid * 4 + 1] = a * wx1 * wy0 * vx1 * vy0;
        s_wgt[tid * 4 + 2] = a * wx0 * wy1 * vx0 * vy1;
        s_wgt[tid * 4 + 3] = a * wx1 * wy1 * vx1 * vy1;
    }
    __syncthreads();

    // augmented columns: S_h and zero padding
    if (tid < 8) {
        float S = 0.0f;
        #pragma unroll
        for (int c = 0; c < 16; ++c) S += s_wgt[tid * 16 + c];
        sv[(size_t)bq * KAUG + 2048 + tid] = f2bf(S);
    } else if (tid < 64) {
        sv[(size_t)bq * KAUG + 2048 + tid] = 0;
    }

    // phase 2: gather
    const int half = lane >> 5;           // corner parity
    const int l5   = lane & 31;           // owns 8 channels
    const unsigned short* ib = val + (size_t)b * HW * D + l5 * 8;

    float acc[2][8] = {};
    #pragma unroll
    for (int g = 0; g < 2; ++g) {         // g == head-within-wave
        ushort8v vb[8];
        float    wg[8];
        #pragma unroll
        for (int j = 0; j < 8; ++j) {     // 8 loads in flight
            const int flat = w * 32 + (g * 8 + j) * 2 + half;
            wg[j] = s_wgt[flat];
            vb[j] = *(const ushort8v*)(ib + (size_t)s_off[flat] * D);
        }
        #pragma unroll
        for (int j = 0; j < 8; ++j)
            #pragma unroll
            for (int k = 0; k < 8; ++k)
                acc[g][k] += wg[j] * bf2f(vb[j][k]);
    }

    #pragma unroll
    for (int hh = 0; hh < 2; ++hh) {
        float comb[8];
        #pragma unroll
        for (int k = 0; k < 8; ++k)
            comb[k] = acc[hh][k] + __shfl_xor(acc[hh][k], 32, 64);
        if (half == 0) {
            const int h = w * 2 + hh;
            ushort8v o;
            #pragma unroll
            for (int k = 0; k < 8; ++k) o[k] = f2bf(comb[k]);
            *(ushort8v*)&sv[(size_t)bq * KAUG + h * D + l5 * 8] = o;
        }
    }
}

// ---------------------------------------------------------------------------
extern "C" void kernel_launch(void* const* d_in, const int* in_sizes, int n_in,
                              void* d_out, int out_size, void* d_ws, size_t ws_size,
                              hipStream_t stream) {
    const float* query  = (const float*)d_in[0];
    const float* refpts = (const float*)d_in[1];
    const float* value  = (const float*)d_in[2];
    const float* W_off  = (const float*)d_in[3];
    const float* b_off  = (const float*)d_in[4];
    const float* W_attn = (const float*)d_in[5];
    const float* b_attn = (const float*)d_in[6];
    const float* W_v    = (const float*)d_in[7];
    const float* b_v    = (const float*)d_in[8];
    const float* W_out  = (const float*)d_in[9];
    const float* b_out  = (const float*)d_in[10];
    float* out = (float*)d_out;

    // workspace layout (byte offsets, all 256B aligned)
    char* wsb = (char*)d_ws;
    unsigned short* val_bf  = (unsigned short*)(wsb);             // 33,554,432 B
    unsigned short* sv      = (unsigned short*)(wsb + 33554432);  // 17,301,504 B
    unsigned short* WcT     = (unsigned short*)(wsb + 50855936);  //  1,081,344 B
    unsigned short* Wout_t  = (unsigned short*)(wsb + 51937280);  //  1,048,576 B
    unsigned short* Wv_bf   = (unsigned short*)(wsb + 52985856);  //    131,072 B
    float*          raw     = (float*)(wsb + 53116928);           //  2,097,152 B
    float*          Woa     = (float*)(wsb + 55214080);           //    131,072 B
    float*          bias_oa = (float*)(wsb + 55345152);           //        512 B

    // 1: mega-prep (streaming only)
    k_prep<<<RB_END, 256, 0, stream>>>(value, W_off, b_off, W_attn, b_attn,
                                       b_v, W_out, W_v,
                                       val_bf, Woa, bias_oa, Wout_t, Wv_bf, WcT);

    // 2: raw = query @ Woa + bias_oa  (fp32, M=4096, N=128, K=256)
    {
        dim3 grid((B * Q) / BM, 128 / BN);
        k_sgemm<<<grid, 256, 0, stream>>>(query, Woa, bias_oa, raw,
                                          B * Q, 128, D);
    }

    // 3: Wc_h = W_v @ W_out_h  -> WcT (batched over h = blockIdx.z)
    {
        dim3 grid(D / 64, D / 64, NH);
        k_gemm64<1><<<grid, 256, 0, stream>>>(Wv_bf, D, Wout_t, NH * D,
                                              nullptr, WcT, KAUG, D);
    }

    // 4: softmax + corner tables + gather + point-reduce -> sv [4096, KAUG]
    k_sample<<<B * Q, 256, 0, stream>>>(val_bf, raw, refpts, sv);

    // 5: out = sv @ WcT^T + b_out  (M=4096, N=256, K=2112)
    {
        dim3 grid((B * Q) / 64, D / 64, 1);
        k_gemm64<0><<<grid, 256, 0, stream>>>(sv, KAUG, WcT, KAUG,
                                              b_out, out, D, KAUG);
    }
}

// Round 9
// 186.612 us; speedup vs baseline: 1.1359x; 1.0565x over previous
//
#include <hip/hip_runtime.h>
#include <hip/hip_bf16.h>
#include <math.h>

// Problem constants (fixed by setup_inputs)
constexpr int B  = 4;
constexpr int Q  = 1024;
constexpr int D  = 256;
constexpr int NH = 8;
constexpr int NP = 4;
constexpr int H  = 128;
constexpr int W  = 128;
constexpr int HW = H * W;
constexpr int KAUG = 2112;          // 8*256 channels + 8 S + 56 zeros (K % 64 == 0)

typedef short   bf16x8  __attribute__((ext_vector_type(8)));
typedef float   f32x4   __attribute__((ext_vector_type(4)));
typedef short   short4v __attribute__((ext_vector_type(4)));
typedef unsigned short ushort8v __attribute__((ext_vector_type(8)));

__device__ inline unsigned short f2bf(float f) {
    union { float f; unsigned u; } v; v.f = f;
    unsigned r = v.u + 0x7fff + ((v.u >> 16) & 1);   // RNE
    return (unsigned short)(r >> 16);
}
__device__ inline float bf2f(unsigned short s) {
    union { unsigned u; float f; } v; v.u = ((unsigned)s) << 16;
    return v.f;
}

// async global->LDS, 16B per lane. LDS dest = wave-uniform base + lane*16.
__device__ inline void async16(const void* g, void* l) {
    __builtin_amdgcn_global_load_lds(
        (const __attribute__((address_space(1))) unsigned*)g,
        (__attribute__((address_space(3))) unsigned*)l, 16, 0, 0);
}

// ---------------------------------------------------------------------------
// Shared bf16 MFMA GEMM body: 64x64 tile, BK=64, double-buffered async16
// staging, XOR-swizzled LDS. lds = 16384 ushorts (32 KB), 4 buffers of 4096.
// C[M,N] = A[M,K](lda) @ Bt[N,K](ldb)^T
// OUTMODE 0: fp32 C row-major (ldc) + bias[N]
// OUTMODE 1: bf16 transposed store Wt[col*ldc + zblk*256 + row]; Bt += zblk*256
// ---------------------------------------------------------------------------
template <int OUTMODE>
__device__ __forceinline__ void gemm64_body(
        unsigned short* __restrict__ lds,
        const unsigned short* __restrict__ A, int lda,
        const unsigned short* __restrict__ Bt, int ldb,
        const float* __restrict__ bias,
        void* __restrict__ Cout, int ldc, int K,
        int m0, int n0, int zblk) {
    const int tid  = threadIdx.x;
    const int lane = tid & 63;
    const int w    = tid >> 6;
    const int wm   = w >> 1, wn = w & 1;
    if (OUTMODE == 1) Bt += (size_t)zblk * 256;

    const int srow = w * 8 + (lane >> 3);
    const int schk = (lane & 7) ^ (lane >> 3);
    const unsigned short* ag0 = A  + (size_t)(m0 + srow)      * lda + schk * 8;
    const unsigned short* ag1 = A  + (size_t)(m0 + srow + 32) * lda + schk * 8;
    const unsigned short* bg0 = Bt + (size_t)(n0 + srow)      * ldb + schk * 8;
    const unsigned short* bg1 = Bt + (size_t)(n0 + srow + 32) * ldb + schk * 8;
    const int l0 = w * 512 + lane * 8;
    const int l1 = l0 + 2048;

    int aoff[2][2], boff[2][2];
    #pragma unroll
    for (int i = 0; i < 2; ++i)
        #pragma unroll
        for (int kk = 0; kk < 2; ++kk) {
            const int ar = wm * 32 + i * 16 + (lane & 15);
            aoff[i][kk] = ar * 64 + ((((lane >> 4) + kk * 4) ^ (ar & 7)) * 8);
            const int br = wn * 32 + i * 16 + (lane & 15);
            boff[i][kk] = br * 64 + ((((lane >> 4) + kk * 4) ^ (br & 7)) * 8);
        }

    f32x4 acc[2][2];
    #pragma unroll
    for (int i = 0; i < 2; ++i)
        #pragma unroll
        for (int j = 0; j < 2; ++j) acc[i][j] = (f32x4){0.f, 0.f, 0.f, 0.f};

    async16(ag0, &lds[0 * 4096 + l0]); async16(ag1, &lds[0 * 4096 + l1]);
    async16(bg0, &lds[1 * 4096 + l0]); async16(bg1, &lds[1 * 4096 + l1]);

    const int niter = K >> 6;
    for (int it = 0; it < niter; ++it) {
        __syncthreads();
        const int cur = (it & 1) * 2;
        if (it + 1 < niter) {
            const int nxt = 2 - cur;
            const int ko  = (it + 1) * 64;
            async16(ag0 + ko, &lds[nxt * 4096 + l0]);
            async16(ag1 + ko, &lds[nxt * 4096 + l1]);
            async16(bg0 + ko, &lds[(nxt + 1) * 4096 + l0]);
            async16(bg1 + ko, &lds[(nxt + 1) * 4096 + l1]);
        }
        bf16x8 af[2][2], bfv[2][2];
        #pragma unroll
        for (int i = 0; i < 2; ++i)
            #pragma unroll
            for (int kk = 0; kk < 2; ++kk) {
                af[i][kk]  = *(const bf16x8*)&lds[cur * 4096 + aoff[i][kk]];
                bfv[i][kk] = *(const bf16x8*)&lds[(cur + 1) * 4096 + boff[i][kk]];
            }
        #pragma unroll
        for (int i = 0; i < 2; ++i)
            #pragma unroll
            for (int j = 0; j < 2; ++j)
                #pragma unroll
                for (int kk = 0; kk < 2; ++kk)
                    acc[i][j] = __builtin_amdgcn_mfma_f32_16x16x32_bf16(
                        af[i][kk], bfv[j][kk], acc[i][j], 0, 0, 0);
    }

    const int colb = n0 + wn * 32 + (lane & 15);
    const int rowb = m0 + wm * 32 + (lane >> 4) * 4;
    if (OUTMODE == 0) {
        float* C = (float*)Cout;
        #pragma unroll
        for (int j = 0; j < 2; ++j) {
            const int col = colb + j * 16;
            const float bb = bias[col];
            #pragma unroll
            for (int i = 0; i < 2; ++i)
                #pragma unroll
                for (int r = 0; r < 4; ++r)
                    C[(size_t)(rowb + i * 16 + r) * ldc + col] = acc[i][j][r] + bb;
        }
    } else {
        unsigned short* Wt = (unsigned short*)Cout;
        const int ocol = zblk * 256;
        #pragma unroll
        for (int j = 0; j < 2; ++j) {
            const int col = colb + j * 16;
            #pragma unroll
            for (int i = 0; i < 2; ++i)
                #pragma unroll
                for (int r = 0; r < 4; ++r)
                    Wt[(size_t)col * ldc + ocol + rowb + i * 16 + r] =
                        f2bf(acc[i][j][r]);
        }
    }
}

// ---------------------------------------------------------------------------
// STAGE 1 (role-merged): all mutually independent prep work.
//   [0, 16384)      : value fp32->bf16 (1024 elems/block)
//   [16384, 16512)  : raw = query @ [W_off|W_attn|0] + bias  (fp32 SGEMM,
//                     B-operand and bias read directly from W_off/W_attn —
//                     no pre-assembled Woa, so no intra-kernel dependency)
//   [16512, 18560)  : W_out [2048,256] -> bf16 transposed Wout_t [256,2048]
//   [18560, 18624)  : W_v fp32->bf16
//   [18624, 18688)  : WcT border-correction cols 2048..2111 (b_v @ W_out_h)
// ---------------------------------------------------------------------------
constexpr int R1_CONV = 0;
constexpr int R1_SG   = R1_CONV + (B * HW * D) / 1024;   // 16384
constexpr int R1_WOUT = R1_SG   + 128;                   // 16512
constexpr int R1_WV   = R1_WOUT + (NH * D * D) / 256;    // 18560
constexpr int R1_BV   = R1_WV   + (D * D) / 1024;        // 18624
constexpr int R1_END  = R1_BV   + (D * 64) / 256;        // 18688

__global__ __launch_bounds__(256)
void k_stage1(const float* __restrict__ value,
              const float* __restrict__ query,
              const float* __restrict__ W_off,  const float* __restrict__ b_off,
              const float* __restrict__ W_attn, const float* __restrict__ b_attn,
              const float* __restrict__ b_v,    const float* __restrict__ W_out,
              const float* __restrict__ W_v,
              unsigned short* __restrict__ val_bf,
              float* __restrict__ raw,          // [B*Q, 128]
              unsigned short* __restrict__ Wout_t,
              unsigned short* __restrict__ Wv_bf,
              unsigned short* __restrict__ WcT) {
    __shared__ __align__(16) float smem[2][16][68];      // 8704 B (sgemm role)
    const int blk = blockIdx.x;
    const int tid = threadIdx.x;

    if (blk < R1_SG) {
        // --- value convert: 1024 elems per block ---
        const int i = (blk * 1024) + tid * 4;
        const float4 v = *(const float4*)&value[i];
        short4v o;
        o.x = (short)f2bf(v.x); o.y = (short)f2bf(v.y);
        o.z = (short)f2bf(v.z); o.w = (short)f2bf(v.w);
        *(short4v*)&val_bf[i] = o;
    } else if (blk < R1_WOUT) {
        // --- fp32 SGEMM role: raw[M=4096, N=128] = query @ Woa + bias ---
        const int blkr = blk - R1_SG;
        const int m0 = (blkr >> 1) * 64;
        const int n0 = (blkr & 1) * 64;
        float (*As)[68] = smem[0];
        float (*Bs)[68] = smem[1];
        const int t  = tid;
        const int tx = t & 15, ty = t >> 4;
        const int arow = t >> 2, akg = (t & 3) * 4;
        const int brow = t >> 4, bcol = (t & 15) * 4;

        float acc[4][4] = {};
        for (int k0 = 0; k0 < D; k0 += 16) {
            const float4 av = *(const float4*)&query[(size_t)(m0 + arow) * D + k0 + akg];
            const int kr = k0 + brow;
            const int j  = n0 + bcol;
            float4 bv;
            if (j < 64)      bv = *(const float4*)&W_off[kr * 64 + j];
            else if (j < 96) bv = *(const float4*)&W_attn[kr * 32 + (j - 64)];
            else             bv = (float4){0.f, 0.f, 0.f, 0.f};
            __syncthreads();
            As[akg + 0][arow] = av.x;
            As[akg + 1][arow] = av.y;
            As[akg + 2][arow] = av.z;
            As[akg + 3][arow] = av.w;
            *(float4*)&Bs[brow][bcol] = bv;
            __syncthreads();
            #pragma unroll
            for (int kk = 0; kk < 16; ++kk) {
                const float4 a = *(const float4*)&As[kk][ty * 4];
                const float4 b = *(const float4*)&Bs[kk][tx * 4];
                acc[0][0] += a.x * b.x; acc[0][1] += a.x * b.y; acc[0][2] += a.x * b.z; acc[0][3] += a.x * b.w;
                acc[1][0] += a.y * b.x; acc[1][1] += a.y * b.y; acc[1][2] += a.y * b.z; acc[1][3] += a.y * b.w;
                acc[2][0] += a.z * b.x; acc[2][1] += a.z * b.y; acc[2][2] += a.z * b.z; acc[2][3] += a.z * b.w;
                acc[3][0] += a.w * b.x; acc[3][1] += a.w * b.y; acc[3][2] += a.w * b.z; acc[3][3] += a.w * b.w;
            }
        }
        float bb[4];
        #pragma unroll
        for (int c = 0; c < 4; ++c) {
            const int col = n0 + tx * 4 + c;
            bb[c] = (col < 64) ? b_off[col] : ((col < 96) ? b_attn[col - 64] : 0.0f);
        }
        #pragma unroll
        for (int i = 0; i < 4; ++i) {
            const int m = m0 + ty * 4 + i;
            float4 r;
            r.x = acc[i][0] + bb[0];
            r.y = acc[i][1] + bb[1];
            r.z = acc[i][2] + bb[2];
            r.w = acc[i][3] + bb[3];
            *(float4*)&raw[(size_t)m * 128 + n0 + tx * 4] = r;
        }
    } else if (blk < R1_WV) {
        // --- W_out [2048,256] -> Wout_t [256,2048] bf16 ---
        const int i = (blk - R1_WOUT) * 256 + tid;   // i = n*2048 + k
        const int n = i >> 11, k = i & 2047;
        Wout_t[i] = f2bf(W_out[(size_t)k * D + n]);
    } else if (blk < R1_BV) {
        // --- W_v fp32->bf16, 1024 elems/block ---
        const int i = (blk - R1_WV) * 1024 + tid * 4;
        const float4 v = *(const float4*)&W_v[i];
        short4v o;
        o.x = (short)f2bf(v.x); o.y = (short)f2bf(v.y);
        o.z = (short)f2bf(v.z); o.w = (short)f2bf(v.w);
        *(short4v*)&Wv_bf[i] = o;
    } else {
        // --- WcT border-correction cols: WcT[n, 2048+c] = b_v . W_out[c*256.., n] ---
        const int t = (blk - R1_BV) * 256 + tid;      // n = t>>6, c = t&63
        const int n = t >> 6, c = t & 63;
        float v = 0.0f;
        if (c < 8) {
            #pragma unroll 8
            for (int j = 0; j < D; ++j)
                v += b_v[j] * W_out[((size_t)c * D + j) * D + n];
        }
        WcT[(size_t)n * KAUG + 2048 + c] = f2bf(v);
    }
}

// ---------------------------------------------------------------------------
// STAGE 2 (role-merged):
//   [0, 4096)     : sample — softmax + corner tables + bilinear gather +
//                   point-reduce -> sv  (one block per (b,q))
//   [4096, 4224)  : Wc_h = W_v @ W_out_h -> WcT (128 blocks = 4x4x8)
// The Wc GEMM hides under the gather; both depend only on stage 1.
// ---------------------------------------------------------------------------
constexpr int R2_WC  = B * Q;        // 4096
constexpr int R2_END = R2_WC + 128;  // 4224

__global__ __launch_bounds__(256)
void k_stage2(const unsigned short* __restrict__ val,   // [B,H,W,D] bf16
              const float* __restrict__ raw,            // [B*Q,128]
              const float* __restrict__ refpts,         // [B,Q,2]
              const unsigned short* __restrict__ Wv_bf,
              const unsigned short* __restrict__ Wout_t,
              unsigned short* __restrict__ sv,          // [B*Q, KAUG]
              unsigned short* __restrict__ WcT) {
    __shared__ __align__(16) unsigned short smem[16384];   // 32 KB
    const int blk = blockIdx.x;
    const int tid = threadIdx.x;

    if (blk >= R2_WC) {
        // --- Wc GEMM role ---
        const int blkr = blk - R2_WC;
        const int z  = blkr >> 4;
        const int m0 = ((blkr >> 2) & 3) * 64;
        const int n0 = (blkr & 3) * 64;
        gemm64_body<1>(smem, Wv_bf, D, Wout_t, NH * D, nullptr, WcT, KAUG, D,
                       m0, n0, z);
        return;
    }

    // --- sample role ---
    const int bq   = blk;                 // b*Q + q
    const int b    = bq >> 10;            // Q = 1024
    const int lane = tid & 63;
    const int w    = tid >> 6;

    float* s_raw = (float*)smem;                    // 512 B
    int*   s_off = (int*)((char*)smem + 512);       // 512 B
    float* s_wgt = (float*)((char*)smem + 1024);    // 512 B

    if (tid < 128) s_raw[tid] = raw[(size_t)bq * 128 + tid];
    __syncthreads();

    if (tid < NH * NP) {                  // tid == hp
        const int h = tid >> 2;
        float m = -1e30f;
        #pragma unroll
        for (int p = 0; p < NP; ++p) m = fmaxf(m, s_raw[64 + h * 4 + p]);
        float s = 0.0f;
        #pragma unroll
        for (int p = 0; p < NP; ++p) s += __expf(s_raw[64 + h * 4 + p] - m);
        const float a = __expf(s_raw[64 + tid] - m) / s;

        const float refx = refpts[(size_t)bq * 2 + 0];
        const float refy = refpts[(size_t)bq * 2 + 1];
        const float gx = fminf(fmaxf(refx + s_raw[tid * 2 + 0] * 0.1f, 0.0f), 1.0f) * 2.0f - 1.0f;
        const float gy = fminf(fmaxf(refy + s_raw[tid * 2 + 1] * 0.1f, 0.0f), 1.0f) * 2.0f - 1.0f;
        const float x  = ((gx + 1.0f) * (float)W - 1.0f) * 0.5f;
        const float y  = ((gy + 1.0f) * (float)H - 1.0f) * 0.5f;
        const float x0f = floorf(x), y0f = floorf(y);
        const float wx1 = x - x0f,  wy1 = y - y0f;
        const float wx0 = 1.0f - wx1, wy0 = 1.0f - wy1;
        const int x0 = (int)x0f, y0 = (int)y0f;
        const int x1 = x0 + 1,  y1 = y0 + 1;
        const float vx0 = (x0 >= 0 && x0 < W) ? 1.0f : 0.0f;
        const float vx1 = (x1 >= 0 && x1 < W) ? 1.0f : 0.0f;
        const float vy0 = (y0 >= 0 && y0 < H) ? 1.0f : 0.0f;
        const float vy1 = (y1 >= 0 && y1 < H) ? 1.0f : 0.0f;
        const int xc0 = min(max(x0, 0), W - 1);
        const int xc1 = min(max(x1, 0), W - 1);
        const int yc0 = min(max(y0, 0), H - 1);
        const int yc1 = min(max(y1, 0), H - 1);
        s_off[tid * 4 + 0] = yc0 * W + xc0;
        s_off[tid * 4 + 1] = yc0 * W + xc1;
        s_off[tid * 4 + 2] = yc1 * W + xc0;
        s_off[tid * 4 + 3] = yc1 * W + xc1;
        s_wgt[tid * 4 + 0] = a * wx0 * wy0 * vx0 * vy0;
        s_wgt[tid * 4 + 1] = a * wx1 * wy0 * vx1 * vy0;
        s_wgt[tid * 4 + 2] = a * wx0 * wy1 * vx0 * vy1;
        s_wgt[tid * 4 + 3] = a * wx1 * wy1 * vx1 * vy1;
    }
    __syncthreads();

    // augmented columns: S_h and zero padding
    if (tid < 8) {
        float S = 0.0f;
        #pragma unroll
        for (int c = 0; c < 16; ++c) S += s_wgt[tid * 16 + c];
        sv[(size_t)bq * KAUG + 2048 + tid] = f2bf(S);
    } else if (tid < 64) {
        sv[(size_t)bq * KAUG + 2048 + tid] = 0;
    }

    // gather: half-wave covers one pixel row (32 lanes x 8 ch = 512 B), so
    // each wave-load fetches TWO corners; halves combined via shfl_xor(32).
    const int half = lane >> 5;
    const int l5   = lane & 31;
    const unsigned short* ib = val + (size_t)b * HW * D + l5 * 8;

    float acc[2][8] = {};
    #pragma unroll
    for (int g = 0; g < 2; ++g) {         // g == head-within-wave
        ushort8v vb[8];
        float    wg[8];
        #pragma unroll
        for (int j = 0; j < 8; ++j) {     // 8 loads in flight
            const int flat = w * 32 + (g * 8 + j) * 2 + half;
            wg[j] = s_wgt[flat];
            vb[j] = *(const ushort8v*)(ib + (size_t)s_off[flat] * D);
        }
        #pragma unroll
        for (int j = 0; j < 8; ++j)
            #pragma unroll
            for (int k = 0; k < 8; ++k)
                acc[g][k] += wg[j] * bf2f(vb[j][k]);
    }

    #pragma unroll
    for (int hh = 0; hh < 2; ++hh) {
        float comb[8];
        #pragma unroll
        for (int k = 0; k < 8; ++k)
            comb[k] = acc[hh][k] + __shfl_xor(acc[hh][k], 32, 64);
        if (half == 0) {
            const int h = w * 2 + hh;
            ushort8v o;
            #pragma unroll
            for (int k = 0; k < 8; ++k) o[k] = f2bf(comb[k]);
            *(ushort8v*)&sv[(size_t)bq * KAUG + h * D + l5 * 8] = o;
        }
    }
}

// ---------------------------------------------------------------------------
// STAGE 3: out = sv @ WcT^T + b_out  (M=4096, N=256, K=2112)
// ---------------------------------------------------------------------------
__global__ __launch_bounds__(256)
void k_stage3(const unsigned short* __restrict__ sv,
              const unsigned short* __restrict__ WcT,
              const float* __restrict__ b_out,
              float* __restrict__ out) {
    __shared__ __align__(16) unsigned short smem[16384];   // 32 KB
    gemm64_body<0>(smem, sv, KAUG, WcT, KAUG, b_out, out, D, KAUG,
                   blockIdx.x * 64, blockIdx.y * 64, 0);
}

// ---------------------------------------------------------------------------
extern "C" void kernel_launch(void* const* d_in, const int* in_sizes, int n_in,
                              void* d_out, int out_size, void* d_ws, size_t ws_size,
                              hipStream_t stream) {
    const float* query  = (const float*)d_in[0];
    const float* refpts = (const float*)d_in[1];
    const float* value  = (const float*)d_in[2];
    const float* W_off  = (const float*)d_in[3];
    const float* b_off  = (const float*)d_in[4];
    const float* W_attn = (const float*)d_in[5];
    const float* b_attn = (const float*)d_in[6];
    const float* W_v    = (const float*)d_in[7];
    const float* b_v    = (const float*)d_in[8];
    const float* W_out  = (const float*)d_in[9];
    const float* b_out  = (const float*)d_in[10];
    float* out = (float*)d_out;

    // workspace layout (byte offsets, all 256B aligned)
    char* wsb = (char*)d_ws;
    unsigned short* val_bf  = (unsigned short*)(wsb);             // 33,554,432 B
    unsigned short* sv      = (unsigned short*)(wsb + 33554432);  // 17,301,504 B
    unsigned short* WcT     = (unsigned short*)(wsb + 50855936);  //  1,081,344 B
    unsigned short* Wout_t  = (unsigned short*)(wsb + 51937280);  //  1,048,576 B
    unsigned short* Wv_bf   = (unsigned short*)(wsb + 52985856);  //    131,072 B
    float*          raw     = (float*)(wsb + 53116928);           //  2,097,152 B

    // 1: prep + raw-SGEMM + weight conversions (all independent roles)
    k_stage1<<<R1_END, 256, 0, stream>>>(value, query, W_off, b_off,
                                         W_attn, b_attn, b_v, W_out, W_v,
                                         val_bf, raw, Wout_t, Wv_bf, WcT);

    // 2: sample -> sv  ||  Wc GEMM -> WcT
    k_stage2<<<R2_END, 256, 0, stream>>>(val_bf, raw, refpts, Wv_bf, Wout_t,
                                         sv, WcT);

    // 3: out = sv @ WcT^T + b_out
    {
        dim3 grid((B * Q) / 64, D / 64);
        k_stage3<<<grid, 256, 0, stream>>>(sv, WcT, b_out, out);
    }
}

// Round 10
// 175.054 us; speedup vs baseline: 1.2109x; 1.0660x over previous
//
#include <hip/hip_runtime.h>
#include <hip/hip_bf16.h>
#include <math.h>

// Problem constants (fixed by setup_inputs)
constexpr int B  = 4;
constexpr int Q  = 1024;
constexpr int D  = 256;
constexpr int NH = 8;
constexpr int NP = 4;
constexpr int H  = 128;
constexpr int W  = 128;
constexpr int HW = H * W;
constexpr int KAUG = 2112;          // 8*256 channels + 8 S + 56 zeros (K % 64 == 0)

typedef short   bf16x8  __attribute__((ext_vector_type(8)));
typedef float   f32x4   __attribute__((ext_vector_type(4)));
typedef short   short4v __attribute__((ext_vector_type(4)));
typedef unsigned short ushort8v __attribute__((ext_vector_type(8)));

__device__ inline unsigned short f2bf(float f) {
    union { float f; unsigned u; } v; v.f = f;
    unsigned r = v.u + 0x7fff + ((v.u >> 16) & 1);   // RNE
    return (unsigned short)(r >> 16);
}
__device__ inline float bf2f(unsigned short s) {
    union { unsigned u; float f; } v; v.u = ((unsigned)s) << 16;
    return v.f;
}

// async global->LDS, 16B per lane. LDS dest = wave-uniform base + lane*16.
__device__ inline void async16(const void* g, void* l) {
    __builtin_amdgcn_global_load_lds(
        (const __attribute__((address_space(1))) unsigned*)g,
        (__attribute__((address_space(3))) unsigned*)l, 16, 0, 0);
}

// ---------------------------------------------------------------------------
// bf16 MFMA GEMM body, 64x64 tile, BK=64, DOUBLE-buffered (32 KB LDS).
// C[M,N] = A[M,K](lda) @ Bt[N,K](ldb)^T; fp32 C row-major + bias.
// ---------------------------------------------------------------------------
__device__ __forceinline__ void gemm64_dbuf(
        unsigned short* __restrict__ lds,      // 16384 ushorts
        const unsigned short* __restrict__ A, int lda,
        const unsigned short* __restrict__ Bt, int ldb,
        const float* __restrict__ bias,
        float* __restrict__ C, int ldc, int K, int m0, int n0) {
    const int tid  = threadIdx.x;
    const int lane = tid & 63;
    const int w    = tid >> 6;
    const int wm   = w >> 1, wn = w & 1;

    const int srow = w * 8 + (lane >> 3);
    const int schk = (lane & 7) ^ (lane >> 3);
    const unsigned short* ag0 = A  + (size_t)(m0 + srow)      * lda + schk * 8;
    const unsigned short* ag1 = A  + (size_t)(m0 + srow + 32) * lda + schk * 8;
    const unsigned short* bg0 = Bt + (size_t)(n0 + srow)      * ldb + schk * 8;
    const unsigned short* bg1 = Bt + (size_t)(n0 + srow + 32) * ldb + schk * 8;
    const int l0 = w * 512 + lane * 8;
    const int l1 = l0 + 2048;

    int aoff[2][2], boff[2][2];
    #pragma unroll
    for (int i = 0; i < 2; ++i)
        #pragma unroll
        for (int kk = 0; kk < 2; ++kk) {
            const int ar = wm * 32 + i * 16 + (lane & 15);
            aoff[i][kk] = ar * 64 + ((((lane >> 4) + kk * 4) ^ (ar & 7)) * 8);
            const int br = wn * 32 + i * 16 + (lane & 15);
            boff[i][kk] = br * 64 + ((((lane >> 4) + kk * 4) ^ (br & 7)) * 8);
        }

    f32x4 acc[2][2];
    #pragma unroll
    for (int i = 0; i < 2; ++i)
        #pragma unroll
        for (int j = 0; j < 2; ++j) acc[i][j] = (f32x4){0.f, 0.f, 0.f, 0.f};

    async16(ag0, &lds[0 * 4096 + l0]); async16(ag1, &lds[0 * 4096 + l1]);
    async16(bg0, &lds[1 * 4096 + l0]); async16(bg1, &lds[1 * 4096 + l1]);

    const int niter = K >> 6;
    for (int it = 0; it < niter; ++it) {
        __syncthreads();
        const int cur = (it & 1) * 2;
        if (it + 1 < niter) {
            const int nxt = 2 - cur;
            const int ko  = (it + 1) * 64;
            async16(ag0 + ko, &lds[nxt * 4096 + l0]);
            async16(ag1 + ko, &lds[nxt * 4096 + l1]);
            async16(bg0 + ko, &lds[(nxt + 1) * 4096 + l0]);
            async16(bg1 + ko, &lds[(nxt + 1) * 4096 + l1]);
        }
        bf16x8 af[2][2], bfv[2][2];
        #pragma unroll
        for (int i = 0; i < 2; ++i)
            #pragma unroll
            for (int kk = 0; kk < 2; ++kk) {
                af[i][kk]  = *(const bf16x8*)&lds[cur * 4096 + aoff[i][kk]];
                bfv[i][kk] = *(const bf16x8*)&lds[(cur + 1) * 4096 + boff[i][kk]];
            }
        #pragma unroll
        for (int i = 0; i < 2; ++i)
            #pragma unroll
            for (int j = 0; j < 2; ++j)
                #pragma unroll
                for (int kk = 0; kk < 2; ++kk)
                    acc[i][j] = __builtin_amdgcn_mfma_f32_16x16x32_bf16(
                        af[i][kk], bfv[j][kk], acc[i][j], 0, 0, 0);
    }

    const int colb = n0 + wn * 32 + (lane & 15);
    const int rowb = m0 + wm * 32 + (lane >> 4) * 4;
    #pragma unroll
    for (int j = 0; j < 2; ++j) {
        const int col = colb + j * 16;
        const float bb = bias[col];
        #pragma unroll
        for (int i = 0; i < 2; ++i)
            #pragma unroll
            for (int r = 0; r < 4; ++r)
                C[(size_t)(rowb + i * 16 + r) * ldc + col] = acc[i][j][r] + bb;
    }
}

// ---------------------------------------------------------------------------
// bf16 MFMA GEMM body, 64x64 tile, BK=64, SINGLE-buffered (16 KB LDS).
// Transposed bf16 store: Wt[col*ldc + zblk*256 + row]; Bt += zblk*256.
// Used only for the 128-block Wc GEMM hidden under the gather.
// ---------------------------------------------------------------------------
__device__ __forceinline__ void gemm64_single_t(
        unsigned short* __restrict__ lds,      // 8192 ushorts
        const unsigned short* __restrict__ A, int lda,
        const unsigned short* __restrict__ Bt, int ldb,
        unsigned short* __restrict__ Wt, int ldc, int K,
        int m0, int n0, int zblk) {
    const int tid  = threadIdx.x;
    const int lane = tid & 63;
    const int w    = tid >> 6;
    const int wm   = w >> 1, wn = w & 1;
    Bt += (size_t)zblk * 256;

    const int srow = w * 8 + (lane >> 3);
    const int schk = (lane & 7) ^ (lane >> 3);
    const unsigned short* ag0 = A  + (size_t)(m0 + srow)      * lda + schk * 8;
    const unsigned short* ag1 = A  + (size_t)(m0 + srow + 32) * lda + schk * 8;
    const unsigned short* bg0 = Bt + (size_t)(n0 + srow)      * ldb + schk * 8;
    const unsigned short* bg1 = Bt + (size_t)(n0 + srow + 32) * ldb + schk * 8;
    const int l0 = w * 512 + lane * 8;
    const int l1 = l0 + 2048;

    int aoff[2][2], boff[2][2];
    #pragma unroll
    for (int i = 0; i < 2; ++i)
        #pragma unroll
        for (int kk = 0; kk < 2; ++kk) {
            const int ar = wm * 32 + i * 16 + (lane & 15);
            aoff[i][kk] = ar * 64 + ((((lane >> 4) + kk * 4) ^ (ar & 7)) * 8);
            const int br = wn * 32 + i * 16 + (lane & 15);
            boff[i][kk] = br * 64 + ((((lane >> 4) + kk * 4) ^ (br & 7)) * 8);
        }

    f32x4 acc[2][2];
    #pragma unroll
    for (int i = 0; i < 2; ++i)
        #pragma unroll
        for (int j = 0; j < 2; ++j) acc[i][j] = (f32x4){0.f, 0.f, 0.f, 0.f};

    const int niter = K >> 6;
    for (int it = 0; it < niter; ++it) {
        __syncthreads();                       // protect prev iter's reads
        const int ko = it * 64;
        async16(ag0 + ko, &lds[l0]);
        async16(ag1 + ko, &lds[l1]);
        async16(bg0 + ko, &lds[4096 + l0]);
        async16(bg1 + ko, &lds[4096 + l1]);
        __syncthreads();                       // drain -> LDS visible
        bf16x8 af[2][2], bfv[2][2];
        #pragma unroll
        for (int i = 0; i < 2; ++i)
            #pragma unroll
            for (int kk = 0; kk < 2; ++kk) {
                af[i][kk]  = *(const bf16x8*)&lds[aoff[i][kk]];
                bfv[i][kk] = *(const bf16x8*)&lds[4096 + boff[i][kk]];
            }
        #pragma unroll
        for (int i = 0; i < 2; ++i)
            #pragma unroll
            for (int j = 0; j < 2; ++j)
                #pragma unroll
                for (int kk = 0; kk < 2; ++kk)
                    acc[i][j] = __builtin_amdgcn_mfma_f32_16x16x32_bf16(
                        af[i][kk], bfv[j][kk], acc[i][j], 0, 0, 0);
    }

    const int colb = n0 + wn * 32 + (lane & 15);
    const int rowb = m0 + wm * 32 + (lane >> 4) * 4;
    const int ocol = zblk * 256;
    #pragma unroll
    for (int j = 0; j < 2; ++j) {
        const int col = colb + j * 16;
        #pragma unroll
        for (int i = 0; i < 2; ++i)
            #pragma unroll
            for (int r = 0; r < 4; ++r)
                Wt[(size_t)col * ldc + ocol + rowb + i * 16 + r] =
                    f2bf(acc[i][j][r]);
    }
}

// ---------------------------------------------------------------------------
// STAGE 1 (role-merged). LONG-LATENCY / LOW-PARALLELISM ROLES FIRST so they
// overlap the streaming conv instead of tailing it (R9 lesson: conv-first
// put the 128-block SGEMM on an empty machine at the end — 46us dispatch).
//   [0, 128)        : raw = query @ [W_off|W_attn|0] + bias (fp32 SGEMM)
//   [128, 192)      : WcT border-correction cols (b_v @ W_out_h)
//   [192, 256)      : W_v fp32->bf16
//   [256, 2304)     : W_out [2048,256] -> bf16 transposed Wout_t [256,2048]
//   [2304, 6400)    : value fp32->bf16 (4096 elems/block)
// ---------------------------------------------------------------------------
constexpr int R1_SG   = 0;
constexpr int R1_BV   = R1_SG   + 128;                   // 128
constexpr int R1_WV   = R1_BV   + (D * 64) / 256;        // 192
constexpr int R1_WOUT = R1_WV   + (D * D) / 1024;        // 256
constexpr int R1_CONV = R1_WOUT + (NH * D * D) / 256;    // 2304
constexpr int R1_END  = R1_CONV + (B * HW * D) / 4096;   // 6400

__global__ __launch_bounds__(256)
void k_stage1(const float* __restrict__ value,
              const float* __restrict__ query,
              const float* __restrict__ W_off,  const float* __restrict__ b_off,
              const float* __restrict__ W_attn, const float* __restrict__ b_attn,
              const float* __restrict__ b_v,    const float* __restrict__ W_out,
              const float* __restrict__ W_v,
              unsigned short* __restrict__ val_bf,
              float* __restrict__ raw,          // [B*Q, 128]
              unsigned short* __restrict__ Wout_t,
              unsigned short* __restrict__ Wv_bf,
              unsigned short* __restrict__ WcT) {
    __shared__ __align__(16) float smem[2][16][68];      // 8704 B (sgemm role)
    const int blk = blockIdx.x;
    const int tid = threadIdx.x;

    if (blk < R1_BV) {
        // --- fp32 SGEMM role: raw[M=4096, N=128] = query @ Woa + bias ---
        const int m0 = (blk >> 1) * 64;
        const int n0 = (blk & 1) * 64;
        float (*As)[68] = smem[0];
        float (*Bs)[68] = smem[1];
        const int tx = tid & 15, ty = tid >> 4;
        const int arow = tid >> 2, akg = (tid & 3) * 4;
        const int brow = tid >> 4, bcol = (tid & 15) * 4;

        float acc[4][4] = {};
        for (int k0 = 0; k0 < D; k0 += 16) {
            const float4 av = *(const float4*)&query[(size_t)(m0 + arow) * D + k0 + akg];
            const int kr = k0 + brow;
            const int j  = n0 + bcol;
            float4 bv;
            if (j < 64)      bv = *(const float4*)&W_off[kr * 64 + j];
            else if (j < 96) bv = *(const float4*)&W_attn[kr * 32 + (j - 64)];
            else             bv = (float4){0.f, 0.f, 0.f, 0.f};
            __syncthreads();
            As[akg + 0][arow] = av.x;
            As[akg + 1][arow] = av.y;
            As[akg + 2][arow] = av.z;
            As[akg + 3][arow] = av.w;
            *(float4*)&Bs[brow][bcol] = bv;
            __syncthreads();
            #pragma unroll
            for (int kk = 0; kk < 16; ++kk) {
                const float4 a = *(const float4*)&As[kk][ty * 4];
                const float4 b = *(const float4*)&Bs[kk][tx * 4];
                acc[0][0] += a.x * b.x; acc[0][1] += a.x * b.y; acc[0][2] += a.x * b.z; acc[0][3] += a.x * b.w;
                acc[1][0] += a.y * b.x; acc[1][1] += a.y * b.y; acc[1][2] += a.y * b.z; acc[1][3] += a.y * b.w;
                acc[2][0] += a.z * b.x; acc[2][1] += a.z * b.y; acc[2][2] += a.z * b.z; acc[2][3] += a.z * b.w;
                acc[3][0] += a.w * b.x; acc[3][1] += a.w * b.y; acc[3][2] += a.w * b.z; acc[3][3] += a.w * b.w;
            }
        }
        float bb[4];
        #pragma unroll
        for (int c = 0; c < 4; ++c) {
            const int col = n0 + tx * 4 + c;
            bb[c] = (col < 64) ? b_off[col] : ((col < 96) ? b_attn[col - 64] : 0.0f);
        }
        #pragma unroll
        for (int i = 0; i < 4; ++i) {
            const int m = m0 + ty * 4 + i;
            float4 r;
            r.x = acc[i][0] + bb[0];
            r.y = acc[i][1] + bb[1];
            r.z = acc[i][2] + bb[2];
            r.w = acc[i][3] + bb[3];
            *(float4*)&raw[(size_t)m * 128 + n0 + tx * 4] = r;
        }
    } else if (blk < R1_WV) {
        // --- WcT border-correction cols: WcT[n, 2048+c] = b_v . W_out[c*256.., n]
        const int t = (blk - R1_BV) * 256 + tid;      // n = t>>6, c = t&63
        const int n = t >> 6, c = t & 63;
        float v = 0.0f;
        if (c < 8) {
            #pragma unroll 8
            for (int j = 0; j < D; ++j)
                v += b_v[j] * W_out[((size_t)c * D + j) * D + n];
        }
        WcT[(size_t)n * KAUG + 2048 + c] = f2bf(v);
    } else if (blk < R1_WOUT) {
        // --- W_v fp32->bf16, 1024 elems/block ---
        const int i = (blk - R1_WV) * 1024 + tid * 4;
        const float4 v = *(const float4*)&W_v[i];
        short4v o;
        o.x = (short)f2bf(v.x); o.y = (short)f2bf(v.y);
        o.z = (short)f2bf(v.z); o.w = (short)f2bf(v.w);
        *(short4v*)&Wv_bf[i] = o;
    } else if (blk < R1_CONV) {
        // --- W_out [2048,256] -> Wout_t [256,2048] bf16 ---
        const int i = (blk - R1_WOUT) * 256 + tid;   // i = n*2048 + k
        const int n = i >> 11, k = i & 2047;
        Wout_t[i] = f2bf(W_out[(size_t)k * D + n]);
    } else {
        // --- value convert: 4096 elems per block (4 coalesced float4/thread)
        const int base = (blk - R1_CONV) * 4096;
        #pragma unroll
        for (int s = 0; s < 4; ++s) {
            const int i = base + s * 1024 + tid * 4;
            const float4 v = *(const float4*)&value[i];
            short4v o;
            o.x = (short)f2bf(v.x); o.y = (short)f2bf(v.y);
            o.z = (short)f2bf(v.z); o.w = (short)f2bf(v.w);
            *(short4v*)&val_bf[i] = o;
        }
    }
}

// ---------------------------------------------------------------------------
// STAGE 2 (role-merged, 16 KB LDS):
//   [0, 4096)     : sample — softmax + corner tables + gather (16 loads in
//                   flight) + point-reduce -> sv  (one block per (b,q))
//   [4096, 4224)  : Wc_h = W_v @ W_out_h -> WcT (single-buffered GEMM)
// ---------------------------------------------------------------------------
constexpr int R2_WC  = B * Q;        // 4096
constexpr int R2_END = R2_WC + 128;  // 4224

__global__ __launch_bounds__(256)
void k_stage2(const unsigned short* __restrict__ val,   // [B,H,W,D] bf16
              const float* __restrict__ raw,            // [B*Q,128]
              const float* __restrict__ refpts,         // [B,Q,2]
              const unsigned short* __restrict__ Wv_bf,
              const unsigned short* __restrict__ Wout_t,
              unsigned short* __restrict__ sv,          // [B*Q, KAUG]
              unsigned short* __restrict__ WcT) {
    __shared__ __align__(16) unsigned short smem[8192];    // 16 KB
    const int blk = blockIdx.x;
    const int tid = threadIdx.x;

    if (blk >= R2_WC) {
        // --- Wc GEMM role (hidden under the gather; perf non-critical) ---
        const int blkr = blk - R2_WC;
        const int z  = blkr >> 4;
        const int m0 = ((blkr >> 2) & 3) * 64;
        const int n0 = (blkr & 3) * 64;
        gemm64_single_t(smem, Wv_bf, D, Wout_t, NH * D, WcT, KAUG, D,
                        m0, n0, z);
        return;
    }

    // --- sample role ---
    const int bq   = blk;                 // b*Q + q
    const int b    = bq >> 10;            // Q = 1024
    const int lane = tid & 63;
    const int w    = tid >> 6;

    float* s_raw = (float*)smem;                    // 512 B
    int*   s_off = (int*)((char*)smem + 512);       // 512 B
    float* s_wgt = (float*)((char*)smem + 1024);    // 512 B

    if (tid < 128) s_raw[tid] = raw[(size_t)bq * 128 + tid];
    __syncthreads();

    if (tid < NH * NP) {                  // tid == hp
        const int h = tid >> 2;
        float m = -1e30f;
        #pragma unroll
        for (int p = 0; p < NP; ++p) m = fmaxf(m, s_raw[64 + h * 4 + p]);
        float s = 0.0f;
        #pragma unroll
        for (int p = 0; p < NP; ++p) s += __expf(s_raw[64 + h * 4 + p] - m);
        const float a = __expf(s_raw[64 + tid] - m) / s;

        const float refx = refpts[(size_t)bq * 2 + 0];
        const float refy = refpts[(size_t)bq * 2 + 1];
        const float gx = fminf(fmaxf(refx + s_raw[tid * 2 + 0] * 0.1f, 0.0f), 1.0f) * 2.0f - 1.0f;
        const float gy = fminf(fmaxf(refy + s_raw[tid * 2 + 1] * 0.1f, 0.0f), 1.0f) * 2.0f - 1.0f;
        const float x  = ((gx + 1.0f) * (float)W - 1.0f) * 0.5f;
        const float y  = ((gy + 1.0f) * (float)H - 1.0f) * 0.5f;
        const float x0f = floorf(x), y0f = floorf(y);
        const float wx1 = x - x0f,  wy1 = y - y0f;
        const float wx0 = 1.0f - wx1, wy0 = 1.0f - wy1;
        const int x0 = (int)x0f, y0 = (int)y0f;
        const int x1 = x0 + 1,  y1 = y0 + 1;
        const float vx0 = (x0 >= 0 && x0 < W) ? 1.0f : 0.0f;
        const float vx1 = (x1 >= 0 && x1 < W) ? 1.0f : 0.0f;
        const float vy0 = (y0 >= 0 && y0 < H) ? 1.0f : 0.0f;
        const float vy1 = (y1 >= 0 && y1 < H) ? 1.0f : 0.0f;
        const int xc0 = min(max(x0, 0), W - 1);
        const int xc1 = min(max(x1, 0), W - 1);
        const int yc0 = min(max(y0, 0), H - 1);
        const int yc1 = min(max(y1, 0), H - 1);
        s_off[tid * 4 + 0] = yc0 * W + xc0;
        s_off[tid * 4 + 1] = yc0 * W + xc1;
        s_off[tid * 4 + 2] = yc1 * W + xc0;
        s_off[tid * 4 + 3] = yc1 * W + xc1;
        s_wgt[tid * 4 + 0] = a * wx0 * wy0 * vx0 * vy0;
        s_wgt[tid * 4 + 1] = a * wx1 * wy0 * vx1 * vy0;
        s_wgt[tid * 4 + 2] = a * wx0 * wy1 * vx0 * vy1;
        s_wgt[tid * 4 + 3] = a * wx1 * wy1 * vx1 * vy1;
    }
    __syncthreads();

    // augmented columns: S_h and zero padding
    if (tid < 8) {
        float S = 0.0f;
        #pragma unroll
        for (int c = 0; c < 16; ++c) S += s_wgt[tid * 16 + c];
        sv[(size_t)bq * KAUG + 2048 + tid] = f2bf(S);
    } else if (tid < 64) {
        sv[(size_t)bq * KAUG + 2048 + tid] = 0;
    }

    // gather: half-wave covers one pixel row (32 lanes x 8 ch = 512 B), each
    // wave-load fetches TWO corners; 16 loads issued back-to-back for MLP;
    // halves combined via shfl_xor(32).
    const int half = lane >> 5;
    const int l5   = lane & 31;
    const unsigned short* ib = val + (size_t)b * HW * D + l5 * 8;

    ushort8v vb[16];
    float    wg[16];
    #pragma unroll
    for (int j = 0; j < 16; ++j) {        // all 16 loads in flight
        const int flat = w * 32 + j * 2 + half;
        wg[j] = s_wgt[flat];
        vb[j] = *(const ushort8v*)(ib + (size_t)s_off[flat] * D);
    }

    float acc[2][8] = {};
    #pragma unroll
    for (int j = 0; j < 16; ++j) {
        const int g = j >> 3;             // head-within-wave
        #pragma unroll
        for (int k = 0; k < 8; ++k)
            acc[g][k] += wg[j] * bf2f(vb[j][k]);
    }

    #pragma unroll
    for (int hh = 0; hh < 2; ++hh) {
        float comb[8];
        #pragma unroll
        for (int k = 0; k < 8; ++k)
            comb[k] = acc[hh][k] + __shfl_xor(acc[hh][k], 32, 64);
        if (half == 0) {
            const int h = w * 2 + hh;
            ushort8v o;
            #pragma unroll
            for (int k = 0; k < 8; ++k) o[k] = f2bf(comb[k]);
            *(ushort8v*)&sv[(size_t)bq * KAUG + h * D + l5 * 8] = o;
        }
    }
}

// ---------------------------------------------------------------------------
// STAGE 3: out = sv @ WcT^T + b_out  (M=4096, N=256, K=2112)
// ---------------------------------------------------------------------------
__global__ __launch_bounds__(256)
void k_stage3(const unsigned short* __restrict__ sv,
              const unsigned short* __restrict__ WcT,
              const float* __restrict__ b_out,
              float* __restrict__ out) {
    __shared__ __align__(16) unsigned short smem[16384];   // 32 KB
    gemm64_dbuf(smem, sv, KAUG, WcT, KAUG, b_out, out, D, KAUG,
                blockIdx.x * 64, blockIdx.y * 64);
}

// ---------------------------------------------------------------------------
extern "C" void kernel_launch(void* const* d_in, const int* in_sizes, int n_in,
                              void* d_out, int out_size, void* d_ws, size_t ws_size,
                              hipStream_t stream) {
    const float* query  = (const float*)d_in[0];
    const float* refpts = (const float*)d_in[1];
    const float* value  = (const float*)d_in[2];
    const float* W_off  = (const float*)d_in[3];
    const float* b_off  = (const float*)d_in[4];
    const float* W_attn = (const float*)d_in[5];
    const float* b_attn = (const float*)d_in[6];
    const float* W_v    = (const float*)d_in[7];
    const float* b_v    = (const float*)d_in[8];
    const float* W_out  = (const float*)d_in[9];
    const float* b_out  = (const float*)d_in[10];
    float* out = (float*)d_out;

    // workspace layout (byte offsets, all 256B aligned)
    char* wsb = (char*)d_ws;
    unsigned short* val_bf  = (unsigned short*)(wsb);             // 33,554,432 B
    unsigned short* sv      = (unsigned short*)(wsb + 33554432);  // 17,301,504 B
    unsigned short* WcT     = (unsigned short*)(wsb + 50855936);  //  1,081,344 B
    unsigned short* Wout_t  = (unsigned short*)(wsb + 51937280);  //  1,048,576 B
    unsigned short* Wv_bf   = (unsigned short*)(wsb + 52985856);  //    131,072 B
    float*          raw     = (float*)(wsb + 53116928);           //  2,097,152 B

    // 1: prep + raw-SGEMM + weight conversions (long-latency roles FIRST)
    k_stage1<<<R1_END, 256, 0, stream>>>(value, query, W_off, b_off,
                                         W_attn, b_attn, b_v, W_out, W_v,
                                         val_bf, raw, Wout_t, Wv_bf, WcT);

    // 2: sample -> sv  ||  Wc GEMM -> WcT
    k_stage2<<<R2_END, 256, 0, stream>>>(val_bf, raw, refpts, Wv_bf, Wout_t,
                                         sv, WcT);

    // 3: out = sv @ WcT^T + b_out
    {
        dim3 grid((B * Q) / 64, D / 64);
        k_stage3<<<grid, 256, 0, stream>>>(sv, WcT, b_out, out);
    }
}

// Round 11
// 170.067 us; speedup vs baseline: 1.2464x; 1.0293x over previous
//
#include <hip/hip_runtime.h>
#include <hip/hip_bf16.h>
#include <math.h>

// Problem constants (fixed by setup_inputs)
constexpr int B  = 4;
constexpr int Q  = 1024;
constexpr int D  = 256;
constexpr int NH = 8;
constexpr int NP = 4;
constexpr int H  = 128;
constexpr int W  = 128;
constexpr int HW = H * W;
constexpr int KAUG = 2112;          // 8*256 channels + 8 S + 56 zeros (K % 64 == 0)

typedef short   bf16x8  __attribute__((ext_vector_type(8)));
typedef float   f32x4   __attribute__((ext_vector_type(4)));
typedef short   short4v __attribute__((ext_vector_type(4)));
typedef unsigned short ushort8v __attribute__((ext_vector_type(8)));

__device__ inline unsigned short f2bf(float f) {
    union { float f; unsigned u; } v; v.f = f;
    unsigned r = v.u + 0x7fff + ((v.u >> 16) & 1);   // RNE
    return (unsigned short)(r >> 16);
}
__device__ inline float bf2f(unsigned short s) {
    union { unsigned u; float f; } v; v.u = ((unsigned)s) << 16;
    return v.f;
}

// async global->LDS, 16B per lane. LDS dest = wave-uniform base + lane*16.
__device__ inline void async16(const void* g, void* l) {
    __builtin_amdgcn_global_load_lds(
        (const __attribute__((address_space(1))) unsigned*)g,
        (__attribute__((address_space(3))) unsigned*)l, 16, 0, 0);
}

// ---------------------------------------------------------------------------
// STAGE 1 (role-merged; long-latency roles first — R9/R10 lesson).
//   [0, 128)      : raw = query @ [W_off|W_attn|0] + bias (fp32 SGEMM)
//   [128, 256)    : Wc_h = W_v @ W_out_h -> WcT, fp32 direct loads with
//                   in-kernel bf16 convert + LDS transpose (no Wout_t/Wv_bf!)
//   [256, 320)    : WcT border-correction cols 2048..2111 (b_v @ W_out_h)
//   [320, 4416)   : value fp32->bf16 (4096 elems/block)
// ---------------------------------------------------------------------------
constexpr int R1_SG   = 0;
constexpr int R1_WC   = R1_SG + 128;                     // 128
constexpr int R1_BV   = R1_WC + 128;                     // 256
constexpr int R1_CONV = R1_BV + (D * 64) / 256;          // 320
constexpr int R1_END  = R1_CONV + (B * HW * D) / 4096;   // 4416

__global__ __launch_bounds__(256)
void k_stage1(const float* __restrict__ value,
              const float* __restrict__ query,
              const float* __restrict__ W_off,  const float* __restrict__ b_off,
              const float* __restrict__ W_attn, const float* __restrict__ b_attn,
              const float* __restrict__ b_v,    const float* __restrict__ W_out,
              const float* __restrict__ W_v,
              unsigned short* __restrict__ val_bf,
              float* __restrict__ raw,          // [B*Q, 128]
              unsigned short* __restrict__ WcT) {
    __shared__ __align__(16) unsigned char smemraw[16384];
    const int blk = blockIdx.x;
    const int tid = threadIdx.x;

    if (blk < R1_WC) {
        // --- fp32 SGEMM role: raw[M=4096, N=128] = query @ [W_off|W_attn|0] ---
        const int m0 = (blk >> 1) * 64;
        const int n0 = (blk & 1) * 64;
        float (*As)[68] = (float (*)[68])smemraw;
        float (*Bs)[68] = As + 16;
        const int tx = tid & 15, ty = tid >> 4;
        const int arow = tid >> 2, akg = (tid & 3) * 4;
        const int brow = tid >> 4, bcol = (tid & 15) * 4;

        float acc[4][4] = {};
        for (int k0 = 0; k0 < D; k0 += 16) {
            const float4 av = *(const float4*)&query[(size_t)(m0 + arow) * D + k0 + akg];
            const int kr = k0 + brow;
            const int j  = n0 + bcol;
            float4 bv;
            if (j < 64)      bv = *(const float4*)&W_off[kr * 64 + j];
            else if (j < 96) bv = *(const float4*)&W_attn[kr * 32 + (j - 64)];
            else             bv = (float4){0.f, 0.f, 0.f, 0.f};
            __syncthreads();
            As[akg + 0][arow] = av.x;
            As[akg + 1][arow] = av.y;
            As[akg + 2][arow] = av.z;
            As[akg + 3][arow] = av.w;
            *(float4*)&Bs[brow][bcol] = bv;
            __syncthreads();
            #pragma unroll
            for (int kk = 0; kk < 16; ++kk) {
                const float4 a = *(const float4*)&As[kk][ty * 4];
                const float4 b = *(const float4*)&Bs[kk][tx * 4];
                acc[0][0] += a.x * b.x; acc[0][1] += a.x * b.y; acc[0][2] += a.x * b.z; acc[0][3] += a.x * b.w;
                acc[1][0] += a.y * b.x; acc[1][1] += a.y * b.y; acc[1][2] += a.y * b.z; acc[1][3] += a.y * b.w;
                acc[2][0] += a.z * b.x; acc[2][1] += a.z * b.y; acc[2][2] += a.z * b.z; acc[2][3] += a.z * b.w;
                acc[3][0] += a.w * b.x; acc[3][1] += a.w * b.y; acc[3][2] += a.w * b.z; acc[3][3] += a.w * b.w;
            }
        }
        float bb[4];
        #pragma unroll
        for (int c = 0; c < 4; ++c) {
            const int col = n0 + tx * 4 + c;
            bb[c] = (col < 64) ? b_off[col] : ((col < 96) ? b_attn[col - 64] : 0.0f);
        }
        #pragma unroll
        for (int i = 0; i < 4; ++i) {
            const int m = m0 + ty * 4 + i;
            float4 r;
            r.x = acc[i][0] + bb[0];
            r.y = acc[i][1] + bb[1];
            r.z = acc[i][2] + bb[2];
            r.w = acc[i][3] + bb[3];
            *(float4*)&raw[(size_t)m * 128 + n0 + tx * 4] = r;
        }
    } else if (blk < R1_BV) {
        // --- Wc GEMM role: WcT[n0+n, z*256 + m0+m] = sum_i W_v[m][i] W_out[z*256+i][n]
        // fp32 global loads -> bf16 convert -> swizzled LDS -> MFMA.
        const int blkr = blk - R1_WC;
        const int z  = blkr >> 4;
        const int m0 = ((blkr >> 2) & 3) * 64;
        const int n0 = (blkr & 3) * 64;
        unsigned short* As = (unsigned short*)smemraw;       // 4096 shorts
        unsigned short* Bs = As + 4096;                      // 4096 shorts
        const int lane = tid & 63;
        const int w    = tid >> 6;
        const int wm   = w >> 1, wn = w & 1;

        int aoff[2][2], boff[2][2];
        #pragma unroll
        for (int i = 0; i < 2; ++i)
            #pragma unroll
            for (int kk = 0; kk < 2; ++kk) {
                const int ar = wm * 32 + i * 16 + (lane & 15);
                aoff[i][kk] = ar * 64 + ((((lane >> 4) + kk * 4) ^ (ar & 7)) * 8);
                const int br = wn * 32 + i * 16 + (lane & 15);
                boff[i][kk] = br * 64 + ((((lane >> 4) + kk * 4) ^ (br & 7)) * 8);
            }

        f32x4 acc[2][2];
        #pragma unroll
        for (int i = 0; i < 2; ++i)
            #pragma unroll
            for (int j = 0; j < 2; ++j) acc[i][j] = (f32x4){0.f, 0.f, 0.f, 0.f};

        for (int it = 0; it < 4; ++it) {       // K=256, BK=64
            const int k0 = it * 64;
            __syncthreads();                   // protect prev iter's frag reads
            // stage A (W_v rows m0..m0+63, cols k0..k0+63): 2 chunks/thread
            #pragma unroll
            for (int s = 0; s < 2; ++s) {
                const int cc = tid + s * 256;  // chunk id in [0,512)
                const int r = cc >> 3, c = cc & 7;
                const float4 v0 = *(const float4*)&W_v[(size_t)(m0 + r) * D + k0 + c * 8];
                const float4 v1 = *(const float4*)&W_v[(size_t)(m0 + r) * D + k0 + c * 8 + 4];
                ushort8v o;
                o[0] = f2bf(v0.x); o[1] = f2bf(v0.y); o[2] = f2bf(v0.z); o[3] = f2bf(v0.w);
                o[4] = f2bf(v1.x); o[5] = f2bf(v1.y); o[6] = f2bf(v1.z); o[7] = f2bf(v1.w);
                *(ushort8v*)&As[r * 64 + ((c ^ (r & 7)) * 8)] = o;
            }
            // stage B transposed: Bs[n][k] = W_out[z*256+k0+k][n0+n]
            {
                const int n = tid & 63, kseg = tid >> 6;
                float vj[16];
                #pragma unroll
                for (int j = 0; j < 16; ++j)
                    vj[j] = W_out[(size_t)(z * 256 + k0 + kseg * 16 + j) * D + n0 + n];
                #pragma unroll
                for (int jj = 0; jj < 2; ++jj) {
                    ushort8v o;
                    #pragma unroll
                    for (int q = 0; q < 8; ++q) o[q] = f2bf(vj[jj * 8 + q]);
                    const int c = kseg * 2 + jj;
                    *(ushort8v*)&Bs[n * 64 + ((c ^ (n & 7)) * 8)] = o;
                }
            }
            __syncthreads();
            bf16x8 af[2][2], bfv[2][2];
            #pragma unroll
            for (int i = 0; i < 2; ++i)
                #pragma unroll
                for (int kk = 0; kk < 2; ++kk) {
                    af[i][kk]  = *(const bf16x8*)&As[aoff[i][kk]];
                    bfv[i][kk] = *(const bf16x8*)&Bs[boff[i][kk]];
                }
            #pragma unroll
            for (int i = 0; i < 2; ++i)
                #pragma unroll
                for (int j = 0; j < 2; ++j)
                    #pragma unroll
                    for (int kk = 0; kk < 2; ++kk)
                        acc[i][j] = __builtin_amdgcn_mfma_f32_16x16x32_bf16(
                            af[i][kk], bfv[j][kk], acc[i][j], 0, 0, 0);
        }

        const int colb = n0 + wn * 32 + (lane & 15);
        const int rowb = m0 + wm * 32 + (lane >> 4) * 4;
        const int ocol = z * 256;
        #pragma unroll
        for (int j = 0; j < 2; ++j) {
            const int col = colb + j * 16;
            #pragma unroll
            for (int i = 0; i < 2; ++i)
                #pragma unroll
                for (int r = 0; r < 4; ++r)
                    WcT[(size_t)col * KAUG + ocol + rowb + i * 16 + r] =
                        f2bf(acc[i][j][r]);
        }
    } else if (blk < R1_CONV) {
        // --- WcT border-correction cols: WcT[n, 2048+c] = b_v . W_out[c*256.., n]
        const int t = (blk - R1_BV) * 256 + tid;      // n = t>>6, c = t&63
        const int n = t >> 6, c = t & 63;
        float v = 0.0f;
        if (c < 8) {
            #pragma unroll 8
            for (int j = 0; j < D; ++j)
                v += b_v[j] * W_out[((size_t)c * D + j) * D + n];
        }
        WcT[(size_t)n * KAUG + 2048 + c] = f2bf(v);
    } else {
        // --- value convert: 4096 elems per block (4 coalesced float4/thread)
        const int base = (blk - R1_CONV) * 4096;
        #pragma unroll
        for (int s = 0; s < 4; ++s) {
            const int i = base + s * 1024 + tid * 4;
            const float4 v = *(const float4*)&value[i];
            short4v o;
            o.x = (short)f2bf(v.x); o.y = (short)f2bf(v.y);
            o.z = (short)f2bf(v.z); o.w = (short)f2bf(v.w);
            *(short4v*)&val_bf[i] = o;
        }
    }
}

// ---------------------------------------------------------------------------
// STAGE 2: pure sample — softmax + corner tables + gather (16 loads in
// flight) + point-reduce -> sv. One block per (b,q), 256 thr = 4 waves.
// ---------------------------------------------------------------------------
__global__ __launch_bounds__(256)
void k_stage2(const unsigned short* __restrict__ val,   // [B,H,W,D] bf16
              const float* __restrict__ raw,            // [B*Q,128]
              const float* __restrict__ refpts,         // [B,Q,2]
              unsigned short* __restrict__ sv) {        // [B*Q, KAUG]
    const int bq   = blockIdx.x;          // b*Q + q
    const int b    = bq >> 10;            // Q = 1024
    const int tid  = threadIdx.x;
    const int lane = tid & 63;
    const int w    = tid >> 6;

    __shared__ float s_raw[128];
    __shared__ int   s_off[128];
    __shared__ float s_wgt[128];

    if (tid < 128) s_raw[tid] = raw[(size_t)bq * 128 + tid];
    __syncthreads();

    if (tid < NH * NP) {                  // tid == hp
        const int h = tid >> 2;
        float m = -1e30f;
        #pragma unroll
        for (int p = 0; p < NP; ++p) m = fmaxf(m, s_raw[64 + h * 4 + p]);
        float s = 0.0f;
        #pragma unroll
        for (int p = 0; p < NP; ++p) s += __expf(s_raw[64 + h * 4 + p] - m);
        const float a = __expf(s_raw[64 + tid] - m) / s;

        const float refx = refpts[(size_t)bq * 2 + 0];
        const float refy = refpts[(size_t)bq * 2 + 1];
        const float gx = fminf(fmaxf(refx + s_raw[tid * 2 + 0] * 0.1f, 0.0f), 1.0f) * 2.0f - 1.0f;
        const float gy = fminf(fmaxf(refy + s_raw[tid * 2 + 1] * 0.1f, 0.0f), 1.0f) * 2.0f - 1.0f;
        const float x  = ((gx + 1.0f) * (float)W - 1.0f) * 0.5f;
        const float y  = ((gy + 1.0f) * (float)H - 1.0f) * 0.5f;
        const float x0f = floorf(x), y0f = floorf(y);
        const float wx1 = x - x0f,  wy1 = y - y0f;
        const float wx0 = 1.0f - wx1, wy0 = 1.0f - wy1;
        const int x0 = (int)x0f, y0 = (int)y0f;
        const int x1 = x0 + 1,  y1 = y0 + 1;
        const float vx0 = (x0 >= 0 && x0 < W) ? 1.0f : 0.0f;
        const float vx1 = (x1 >= 0 && x1 < W) ? 1.0f : 0.0f;
        const float vy0 = (y0 >= 0 && y0 < H) ? 1.0f : 0.0f;
        const float vy1 = (y1 >= 0 && y1 < H) ? 1.0f : 0.0f;
        const int xc0 = min(max(x0, 0), W - 1);
        const int xc1 = min(max(x1, 0), W - 1);
        const int yc0 = min(max(y0, 0), H - 1);
        const int yc1 = min(max(y1, 0), H - 1);
        s_off[tid * 4 + 0] = yc0 * W + xc0;
        s_off[tid * 4 + 1] = yc0 * W + xc1;
        s_off[tid * 4 + 2] = yc1 * W + xc0;
        s_off[tid * 4 + 3] = yc1 * W + xc1;
        s_wgt[tid * 4 + 0] = a * wx0 * wy0 * vx0 * vy0;
        s_wgt[tid * 4 + 1] = a * wx1 * wy0 * vx1 * vy0;
        s_wgt[tid * 4 + 2] = a * wx0 * wy1 * vx0 * vy1;
        s_wgt[tid * 4 + 3] = a * wx1 * wy1 * vx1 * vy1;
    }
    __syncthreads();

    // augmented columns: S_h and zero padding
    if (tid < 8) {
        float S = 0.0f;
        #pragma unroll
        for (int c = 0; c < 16; ++c) S += s_wgt[tid * 16 + c];
        sv[(size_t)bq * KAUG + 2048 + tid] = f2bf(S);
    } else if (tid < 64) {
        sv[(size_t)bq * KAUG + 2048 + tid] = 0;
    }

    // gather: half-wave covers one pixel row (32 lanes x 8 ch = 512 B), each
    // wave-load fetches TWO corners; 16 loads issued back-to-back for MLP;
    // halves combined via shfl_xor(32).
    const int half = lane >> 5;
    const int l5   = lane & 31;
    const unsigned short* ib = val + (size_t)b * HW * D + l5 * 8;

    ushort8v vb[16];
    float    wg[16];
    #pragma unroll
    for (int j = 0; j < 16; ++j) {        // all 16 loads in flight
        const int flat = w * 32 + j * 2 + half;
        wg[j] = s_wgt[flat];
        vb[j] = *(const ushort8v*)(ib + (size_t)s_off[flat] * D);
    }

    float acc[2][8] = {};
    #pragma unroll
    for (int j = 0; j < 16; ++j) {
        const int g = j >> 3;             // head-within-wave
        #pragma unroll
        for (int k = 0; k < 8; ++k)
            acc[g][k] += wg[j] * bf2f(vb[j][k]);
    }

    #pragma unroll
    for (int hh = 0; hh < 2; ++hh) {
        float comb[8];
        #pragma unroll
        for (int k = 0; k < 8; ++k)
            comb[k] = acc[hh][k] + __shfl_xor(acc[hh][k], 32, 64);
        if (half == 0) {
            const int h = w * 2 + hh;
            ushort8v o;
            #pragma unroll
            for (int k = 0; k < 8; ++k) o[k] = f2bf(comb[k]);
            *(ushort8v*)&sv[(size_t)bq * KAUG + h * D + l5 * 8] = o;
        }
    }
}

// ---------------------------------------------------------------------------
// STAGE 3: out = sv @ WcT^T + b_out  (M=4096, N=256, K=2112)
// 32x64 tile, BK=64, double-buffered async16, grid (128,4) = 512 blocks
// -> 2 blocks/CU for latency hiding (R10: 64x64 grid 256 was 1 block/CU).
// 4 waves: wave w computes 32M x 16N (cols w*16..w*16+15).
// LDS: A dbuf 2x4KB + B dbuf 2x8KB = 24 KB.
// ---------------------------------------------------------------------------
__global__ __launch_bounds__(256)
void k_stage3(const unsigned short* __restrict__ sv,
              const unsigned short* __restrict__ WcT,
              const float* __restrict__ b_out,
              float* __restrict__ out) {
    __shared__ __align__(16) unsigned short lds[12288];  // [A0|B0|A1|B1] = 2k|4k|2k|4k

    const int tid  = threadIdx.x;
    const int lane = tid & 63;
    const int w    = tid >> 6;
    const int m0 = blockIdx.x * 32, n0 = blockIdx.y * 64;

    // staging: wave w stages A rows w*8+(lane>>3) (32 rows total) and B rows
    // same + same+32 (64 rows); chunk schk swizzled to match frag reads.
    const int srow = w * 8 + (lane >> 3);
    const int schk = (lane & 7) ^ (lane >> 3);
    const unsigned short* ag  = sv  + (size_t)(m0 + srow)      * KAUG + schk * 8;
    const unsigned short* bg0 = WcT + (size_t)(n0 + srow)      * KAUG + schk * 8;
    const unsigned short* bg1 = WcT + (size_t)(n0 + srow + 32) * KAUG + schk * 8;
    const int la = w * 512 + lane * 8;            // within A buf (2048 shorts)
    const int lb = la;                            // within B buf low half

    int aoff[2][2], boff[2];
    #pragma unroll
    for (int i = 0; i < 2; ++i)
        #pragma unroll
        for (int kk = 0; kk < 2; ++kk) {
            const int ar = i * 16 + (lane & 15);
            aoff[i][kk] = ar * 64 + ((((lane >> 4) + kk * 4) ^ (ar & 7)) * 8);
        }
    #pragma unroll
    for (int kk = 0; kk < 2; ++kk) {
        const int br = w * 16 + (lane & 15);
        boff[kk] = br * 64 + ((((lane >> 4) + kk * 4) ^ (br & 7)) * 8);
    }

    f32x4 acc[2];
    acc[0] = (f32x4){0.f, 0.f, 0.f, 0.f};
    acc[1] = (f32x4){0.f, 0.f, 0.f, 0.f};

    // buffers: A at stage*6144, B at stage*6144 + 2048
    async16(ag,  &lds[0 + la]);
    async16(bg0, &lds[2048 + lb]);
    async16(bg1, &lds[2048 + 2048 + lb]);

    const int niter = KAUG >> 6;                  // 33
    for (int it = 0; it < niter; ++it) {
        __syncthreads();
        const int cur = (it & 1) * 6144;
        if (it + 1 < niter) {
            const int nxt = 6144 - cur;
            const int ko  = (it + 1) * 64;
            async16(ag + ko,  &lds[nxt + la]);
            async16(bg0 + ko, &lds[nxt + 2048 + lb]);
            async16(bg1 + ko, &lds[nxt + 4096 + lb]);
        }
        bf16x8 af[2][2], bfv[2];
        #pragma unroll
        for (int kk = 0; kk < 2; ++kk) {
            bfv[kk] = *(const bf16x8*)&lds[cur + 2048 + boff[kk]];
            #pragma unroll
            for (int i = 0; i < 2; ++i)
                af[i][kk] = *(const bf16x8*)&lds[cur + aoff[i][kk]];
        }
        #pragma unroll
        for (int i = 0; i < 2; ++i)
            #pragma unroll
            for (int kk = 0; kk < 2; ++kk)
                acc[i] = __builtin_amdgcn_mfma_f32_16x16x32_bf16(
                    af[i][kk], bfv[kk], acc[i], 0, 0, 0);
    }

    const int col = n0 + w * 16 + (lane & 15);
    const float bb = b_out[col];
    const int rowb = m0 + (lane >> 4) * 4;
    #pragma unroll
    for (int i = 0; i < 2; ++i)
        #pragma unroll
        for (int r = 0; r < 4; ++r)
            out[(size_t)(rowb + i * 16 + r) * D + col] = acc[i][r] + bb;
}

// ---------------------------------------------------------------------------
extern "C" void kernel_launch(void* const* d_in, const int* in_sizes, int n_in,
                              void* d_out, int out_size, void* d_ws, size_t ws_size,
                              hipStream_t stream) {
    const float* query  = (const float*)d_in[0];
    const float* refpts = (const float*)d_in[1];
    const float* value  = (const float*)d_in[2];
    const float* W_off  = (const float*)d_in[3];
    const float* b_off  = (const float*)d_in[4];
    const float* W_attn = (const float*)d_in[5];
    const float* b_attn = (const float*)d_in[6];
    const float* W_v    = (const float*)d_in[7];
    const float* b_v    = (const float*)d_in[8];
    const float* W_out  = (const float*)d_in[9];
    const float* b_out  = (const float*)d_in[10];
    float* out = (float*)d_out;

    // workspace layout (byte offsets, all 256B aligned)
    char* wsb = (char*)d_ws;
    unsigned short* val_bf = (unsigned short*)(wsb);             // 33,554,432 B
    unsigned short* sv     = (unsigned short*)(wsb + 33554432);  // 17,301,504 B
    unsigned short* WcT    = (unsigned short*)(wsb + 50855936);  //  1,081,344 B
    float*          raw    = (float*)(wsb + 51937280);           //  2,097,152 B

    // 1: raw-SGEMM | Wc GEMM (fp32 in) | b_v cols | value conv
    k_stage1<<<R1_END, 256, 0, stream>>>(value, query, W_off, b_off,
                                         W_attn, b_attn, b_v, W_out, W_v,
                                         val_bf, raw, WcT);

    // 2: sample -> sv
    k_stage2<<<B * Q, 256, 0, stream>>>(val_bf, raw, refpts, sv);

    // 3: out = sv @ WcT^T + b_out
    {
        dim3 grid((B * Q) / 32, D / 64);
        k_stage3<<<grid, 256, 0, stream>>>(sv, WcT, b_out, out);
    }
}